// Round 1
// baseline (1100.884 us; speedup 1.0000x reference)
//
#include <hip/hip_runtime.h>
#include <stdint.h>

#define NB 64     // batch
#define NP 4096   // points per batch
#define ND 3      // dim
#define NL 128    // chain length / projections
#define BT 256    // block threads for dist kernel

// ---------------- JAX threefry2x32 (20 rounds) ----------------
__device__ __forceinline__ uint32_t rotl32(uint32_t v, int r) {
  return (v << r) | (v >> (32 - r));
}

__device__ __forceinline__ void threefry2x32(uint32_t k0, uint32_t k1,
                                             uint32_t c0, uint32_t c1,
                                             uint32_t& o0, uint32_t& o1) {
  uint32_t ks2 = k0 ^ k1 ^ 0x1BD11BDAu;
  uint32_t x0 = c0 + k0;
  uint32_t x1 = c1 + k1;
#define TF_RND(R) { x0 += x1; x1 = rotl32(x1, (R)); x1 ^= x0; }
  TF_RND(13) TF_RND(15) TF_RND(26) TF_RND(6)
  x0 += k1;  x1 += ks2 + 1u;
  TF_RND(17) TF_RND(29) TF_RND(16) TF_RND(24)
  x0 += ks2; x1 += k0 + 2u;
  TF_RND(13) TF_RND(15) TF_RND(26) TF_RND(6)
  x0 += k0;  x1 += k1 + 3u;
  TF_RND(17) TF_RND(29) TF_RND(16) TF_RND(24)
  x0 += k1;  x1 += ks2 + 4u;
  TF_RND(13) TF_RND(15) TF_RND(26) TF_RND(6)
  x0 += ks2; x1 += k0 + 5u;
#undef TF_RND
  o0 = x0; o1 = x1;
}

// ---------------- XLA ErfInv32 ----------------
__device__ __forceinline__ float erfinv_f(float x) {
  float w = -log1pf(-x * x);
  float p;
  if (w < 5.0f) {
    w = w - 2.5f;
    p = 2.81022636e-08f;
    p = fmaf(p, w, 3.43273939e-07f);
    p = fmaf(p, w, -3.5233877e-06f);
    p = fmaf(p, w, -4.39150654e-06f);
    p = fmaf(p, w, 0.00021858087f);
    p = fmaf(p, w, -0.00125372503f);
    p = fmaf(p, w, -0.00417768164f);
    p = fmaf(p, w, 0.246640727f);
    p = fmaf(p, w, 1.50140941f);
  } else {
    w = sqrtf(w) - 3.0f;
    p = -0.000200214257f;
    p = fmaf(p, w, 0.000100950558f);
    p = fmaf(p, w, 0.00134934322f);
    p = fmaf(p, w, -0.00367342844f);
    p = fmaf(p, w, 0.00573950773f);
    p = fmaf(p, w, -0.0076224613f);
    p = fmaf(p, w, 0.00943887047f);
    p = fmaf(p, w, 1.00167406f);
    p = fmaf(p, w, 2.83297682f);
  }
  return p * x;
}

// bits -> standard normal, exactly like jax.random.normal (float32 path)
__device__ __forceinline__ float bits_to_normal(uint32_t bits) {
  float f = __uint_as_float((bits >> 9) | 0x3F800000u) - 1.0f;  // [0,1)
  const float LO = -0.99999994f;  // nextafter(-1, 0)
  float u = fmaf(f, 2.0f, LO);    // (hi-lo) rounds to exactly 2.0f
  u = fmaxf(LO, u);
  return 1.41421354f * erfinv_f(u);  // float32(sqrt(2)) * erfinv
}

// bits -> uniform [0,1)
__device__ __forceinline__ float bits_to_unif01(uint32_t bits) {
  float f = __uint_as_float((bits >> 9) | 0x3F800000u) - 1.0f;
  return fmaxf(0.0f, f);
}

// ---------------- Kernel A: generate thetas (normalized) + log-uniforms ----
// grid = NL blocks, 128 threads
__global__ __launch_bounds__(128) void rng_kernel(float* __restrict__ theta,
                                                  float* __restrict__ logu) {
  const int l = blockIdx.x;
  const int tid = threadIdx.x;

  // key = jax.random.key(42) -> (0, 42); key_l = fold_in(key, l) = threefry(key, (0,l))
  uint32_t kl0, kl1;
  threefry2x32(0u, 42u, 0u, (uint32_t)l, kl0, kl1);

  uint32_t na0 = kl0, na1 = kl1;  // key for normal draw
  uint32_t nb0 = 0u, nb1 = 0u;    // key for accept-uniform draw
  if (l > 0) {
    // split(key_l, 2): counts iota(4) -> blocks (0,2) and (1,3)
    uint32_t a0, b0, a1, b1;
    threefry2x32(kl0, kl1, 0u, 2u, a0, b0);
    threefry2x32(kl0, kl1, 1u, 3u, a1, b1);
    na0 = a0; na1 = a1;  // ka = first output words
    nb0 = b0; nb1 = b1;  // kb = second output words
  }

  __shared__ float vals[NB * ND];  // 192 raw normals, row-major (b, d)
  if (tid < 96) {
    // random_bits for shape (64,3): 192 words; block i covers counts (i, 96+i)
    uint32_t o0, o1;
    threefry2x32(na0, na1, (uint32_t)tid, (uint32_t)(96 + tid), o0, o1);
    vals[tid] = bits_to_normal(o0);
    vals[96 + tid] = bits_to_normal(o1);
  }
  __syncthreads();

  if (tid < NB) {
    float v0 = vals[tid * 3 + 0];
    float v1 = vals[tid * 3 + 1];
    float v2 = vals[tid * 3 + 2];
    float s = sqrtf(v0 * v0 + v1 * v1 + v2 * v2);
    float* tp = theta + ((size_t)l * NB + tid) * 3;
    tp[0] = v0 / s;
    tp[1] = v1 / s;
    tp[2] = v2 / s;
  }

  if (l > 0 && tid < 32) {
    // random_bits for shape (64,): 64 words; block i covers counts (i, 32+i)
    uint32_t o0, o1;
    threefry2x32(nb0, nb1, (uint32_t)tid, (uint32_t)(32 + tid), o0, o1);
    logu[l * NB + tid] = logf(bits_to_unif01(o0));
    logu[l * NB + 32 + tid] = logf(bits_to_unif01(o1));
  }
}

// ---------------- Kernel B: project + bitonic sort + squared diff ----------
// grid = NB*NL blocks (bid = b*NL + l), BT threads
__global__ __launch_bounds__(BT) void dist_kernel(const float* __restrict__ x,
                                                  const float* __restrict__ y,
                                                  const float* __restrict__ theta,
                                                  float* __restrict__ dist) {
  __shared__ float sx[NP];
  __shared__ float sy[NP];
  __shared__ float red[BT / 64];

  const int bid = blockIdx.x;
  const int l = bid & (NL - 1);
  const int b = bid >> 7;
  const int tid = threadIdx.x;

  const float* tp = theta + ((size_t)l * NB + b) * 3;
  const float t0 = tp[0];
  const float t1 = tp[1];
  const float t2 = tp[2];

  const float* xb = x + (size_t)b * NP * ND;
  const float* yb = y + (size_t)b * NP * ND;
  for (int i = tid; i < NP; i += BT) {
    const float* px = xb + i * 3;
    sx[i] = px[0] * t0 + px[1] * t1 + px[2] * t2;
    const float* py = yb + i * 3;
    sy[i] = py[0] * t0 + py[1] * t1 + py[2] * t2;
  }

  // bitonic sort both arrays, ascending
  for (int k = 2; k <= NP; k <<= 1) {
    for (int j = k >> 1; j > 0; j >>= 1) {
      __syncthreads();
#pragma unroll
      for (int r = 0; r < NP / 2 / BT; ++r) {
        int pr = tid + r * BT;                      // pair index 0..2047
        int i = ((pr & ~(j - 1)) << 1) | (pr & (j - 1));
        int q = i | j;
        bool up = (i & k) == 0;
        float a = sx[i], c = sx[q];
        if ((a > c) == up) { sx[i] = c; sx[q] = a; }
        float e = sy[i], f = sy[q];
        if ((e > f) == up) { sy[i] = f; sy[q] = e; }
      }
    }
  }
  __syncthreads();

  float s = 0.0f;
  for (int i = tid; i < NP; i += BT) {
    float d = sx[i] - sy[i];
    s = fmaf(d, d, s);
  }
  for (int off = 32; off; off >>= 1) s += __shfl_down(s, off);
  if ((tid & 63) == 0) red[tid >> 6] = s;
  __syncthreads();
  if (tid == 0) {
    float tot = 0.0f;
    for (int w = 0; w < BT / 64; ++w) tot += red[w];
    dist[l * NB + b] = tot;
  }
}

// ---------------- Kernel C: IMH chain + loss reduction ----------------
// 1 block, 64 threads (one per batch element)
__global__ __launch_bounds__(64) void chain_kernel(const float* __restrict__ dist,
                                                   const float* __restrict__ logu,
                                                   float* __restrict__ out) {
  const int b = threadIdx.x;
  float dold = dist[b];  // l = 0
  float sum = dold;
  for (int l = 1; l < NL; ++l) {
    float dn = dist[l * NB + b];
    float acc = fminf(0.0f, dn - dold);
    if (logu[l * NB + b] <= acc) dold = dn;
    sum += dold;
  }
  float v = sqrtf(sum * (1.0f / (float)NL));
  for (int off = 32; off; off >>= 1) v += __shfl_down(v, off);
  if (b == 0) out[0] = v * (1.0f / (float)NB);
}

extern "C" void kernel_launch(void* const* d_in, const int* in_sizes, int n_in,
                              void* d_out, int out_size, void* d_ws, size_t ws_size,
                              hipStream_t stream) {
  const float* x = (const float*)d_in[0];
  const float* y = (const float*)d_in[1];
  float* out = (float*)d_out;

  float* theta = (float*)d_ws;              // NL*NB*3 floats
  float* logu = theta + NL * NB * 3;        // NL*NB floats
  float* dist = logu + NL * NB;             // NL*NB floats

  hipLaunchKernelGGL(rng_kernel, dim3(NL), dim3(128), 0, stream, theta, logu);
  hipLaunchKernelGGL(dist_kernel, dim3(NB * NL), dim3(BT), 0, stream, x, y, theta, dist);
  hipLaunchKernelGGL(chain_kernel, dim3(1), dim3(64), 0, stream, dist, logu, out);
}

// Round 2
// 487.597 us; speedup vs baseline: 2.2578x; 2.2578x over previous
//
#include <hip/hip_runtime.h>
#include <stdint.h>

#define NB 64     // batch
#define NP 4096   // points per batch
#define ND 3      // dim
#define NL 128    // chain length / projections
#define BT 256    // block threads for dist kernel
#define V 16      // elements per thread per array (NP/BT)

// ---------------- JAX threefry2x32 (20 rounds) ----------------
__device__ __forceinline__ uint32_t rotl32(uint32_t v, int r) {
  return (v << r) | (v >> (32 - r));
}

__device__ __forceinline__ void threefry2x32(uint32_t k0, uint32_t k1,
                                             uint32_t c0, uint32_t c1,
                                             uint32_t& o0, uint32_t& o1) {
  uint32_t ks2 = k0 ^ k1 ^ 0x1BD11BDAu;
  uint32_t x0 = c0 + k0;
  uint32_t x1 = c1 + k1;
#define TF_RND(R) { x0 += x1; x1 = rotl32(x1, (R)); x1 ^= x0; }
  TF_RND(13) TF_RND(15) TF_RND(26) TF_RND(6)
  x0 += k1;  x1 += ks2 + 1u;
  TF_RND(17) TF_RND(29) TF_RND(16) TF_RND(24)
  x0 += ks2; x1 += k0 + 2u;
  TF_RND(13) TF_RND(15) TF_RND(26) TF_RND(6)
  x0 += k0;  x1 += k1 + 3u;
  TF_RND(17) TF_RND(29) TF_RND(16) TF_RND(24)
  x0 += k1;  x1 += ks2 + 4u;
  TF_RND(13) TF_RND(15) TF_RND(26) TF_RND(6)
  x0 += ks2; x1 += k0 + 5u;
#undef TF_RND
  o0 = x0; o1 = x1;
}

// ---------------- XLA ErfInv32 ----------------
__device__ __forceinline__ float erfinv_f(float x) {
  float w = -log1pf(-x * x);
  float p;
  if (w < 5.0f) {
    w = w - 2.5f;
    p = 2.81022636e-08f;
    p = fmaf(p, w, 3.43273939e-07f);
    p = fmaf(p, w, -3.5233877e-06f);
    p = fmaf(p, w, -4.39150654e-06f);
    p = fmaf(p, w, 0.00021858087f);
    p = fmaf(p, w, -0.00125372503f);
    p = fmaf(p, w, -0.00417768164f);
    p = fmaf(p, w, 0.246640727f);
    p = fmaf(p, w, 1.50140941f);
  } else {
    w = sqrtf(w) - 3.0f;
    p = -0.000200214257f;
    p = fmaf(p, w, 0.000100950558f);
    p = fmaf(p, w, 0.00134934322f);
    p = fmaf(p, w, -0.00367342844f);
    p = fmaf(p, w, 0.00573950773f);
    p = fmaf(p, w, -0.0076224613f);
    p = fmaf(p, w, 0.00943887047f);
    p = fmaf(p, w, 1.00167406f);
    p = fmaf(p, w, 2.83297682f);
  }
  return p * x;
}

__device__ __forceinline__ float bits_to_normal(uint32_t bits) {
  float f = __uint_as_float((bits >> 9) | 0x3F800000u) - 1.0f;  // [0,1)
  const float LO = -0.99999994f;  // nextafter(-1, 0)
  float u = fmaf(f, 2.0f, LO);
  u = fmaxf(LO, u);
  return 1.41421354f * erfinv_f(u);
}

__device__ __forceinline__ float bits_to_unif01(uint32_t bits) {
  float f = __uint_as_float((bits >> 9) | 0x3F800000u) - 1.0f;
  return fmaxf(0.0f, f);
}

// ---------------- Kernel A: thetas (normalized) + log-uniforms ----------
__global__ __launch_bounds__(128) void rng_kernel(float* __restrict__ theta,
                                                  float* __restrict__ logu) {
  const int l = blockIdx.x;
  const int tid = threadIdx.x;

  uint32_t kl0, kl1;
  threefry2x32(0u, 42u, 0u, (uint32_t)l, kl0, kl1);

  uint32_t na0 = kl0, na1 = kl1;
  uint32_t nb0 = 0u, nb1 = 0u;
  if (l > 0) {
    uint32_t a0, b0, a1, b1;
    threefry2x32(kl0, kl1, 0u, 2u, a0, b0);
    threefry2x32(kl0, kl1, 1u, 3u, a1, b1);
    na0 = a0; na1 = a1;
    nb0 = b0; nb1 = b1;
  }

  __shared__ float vals[NB * ND];
  if (tid < 96) {
    uint32_t o0, o1;
    threefry2x32(na0, na1, (uint32_t)tid, (uint32_t)(96 + tid), o0, o1);
    vals[tid] = bits_to_normal(o0);
    vals[96 + tid] = bits_to_normal(o1);
  }
  __syncthreads();

  if (tid < NB) {
    float v0 = vals[tid * 3 + 0];
    float v1 = vals[tid * 3 + 1];
    float v2 = vals[tid * 3 + 2];
    float s = sqrtf(v0 * v0 + v1 * v1 + v2 * v2);
    float* tp = theta + ((size_t)l * NB + tid) * 3;
    tp[0] = v0 / s;
    tp[1] = v1 / s;
    tp[2] = v2 / s;
  }

  if (l > 0 && tid < 32) {
    uint32_t o0, o1;
    threefry2x32(nb0, nb1, (uint32_t)tid, (uint32_t)(32 + tid), o0, o1);
    logu[l * NB + tid] = logf(bits_to_unif01(o0));
    logu[l * NB + 32 + tid] = logf(bits_to_unif01(o1));
  }
}

// ---------------- register-blocked bitonic helpers ----------------

// in-register stage, compile-time direction from v (initial k<=8 phases)
template<int K, int J>
__device__ __forceinline__ void reg_stage_static(float (&r)[V]) {
#pragma unroll
  for (int v = 0; v < V; ++v)
    if ((v & J) == 0) {
      const bool up = (v & K) == 0;
      float mn = fminf(r[v], r[v | J]);
      float mx = fmaxf(r[v], r[v | J]);
      r[v] = up ? mn : mx;
      r[v | J] = up ? mx : mn;
    }
}

// in-register stage, runtime (per-thread) direction
template<int J>
__device__ __forceinline__ void reg_stage(float (&r)[V], bool up) {
#pragma unroll
  for (int v = 0; v < V; ++v)
    if ((v & J) == 0) {
      float mn = fminf(r[v], r[v | J]);
      float mx = fmaxf(r[v], r[v | J]);
      r[v] = up ? mn : mx;
      r[v | J] = up ? mx : mn;
    }
}

// cross-lane stage via shuffle: j = 16*m, m in {1..32}
__device__ __forceinline__ void shfl_stage(float (&r)[V], int tid, int m, bool up) {
  const bool keepmin = (((tid & m) == 0) == up);
#pragma unroll
  for (int v = 0; v < V; ++v) {
    float p = __shfl_xor(r[v], m, 64);
    float mn = fminf(r[v], p);
    float mx = fmaxf(r[v], p);
    r[v] = keepmin ? mn : mx;
  }
}

// cross-wave stage j = 1024 (lane distance 64) for phase k=2048
__device__ __forceinline__ void lds_stage64(float (&r)[V], int tid, float* buf, bool up) {
  __syncthreads();
#pragma unroll
  for (int v = 0; v < V; ++v) buf[v * BT + tid] = r[v];
  __syncthreads();
  const bool keepmin = (((tid & 64) == 0) == up);
#pragma unroll
  for (int v = 0; v < V; ++v) {
    float p = buf[v * BT + (tid ^ 64)];
    float mn = fminf(r[v], p);
    float mx = fmaxf(r[v], p);
    r[v] = keepmin ? mn : mx;
  }
}

// fused j=2048 + j=1024 stages of the final k=4096 phase (up == true)
__device__ __forceinline__ void lds_stage_4096(float (&r)[V], int tid, float* buf) {
  __syncthreads();
#pragma unroll
  for (int v = 0; v < V; ++v) buf[v * BT + tid] = r[v];
  __syncthreads();
  const bool low128 = (tid & 128) == 0;
  const bool low64 = (tid & 64) == 0;
#pragma unroll
  for (int v = 0; v < V; ++v) {
    float a = r[v];
    float b = buf[v * BT + (tid ^ 128)];
    float c = buf[v * BT + (tid ^ 64)];
    float d = buf[v * BT + (tid ^ 192)];
    float a1 = low128 ? fminf(a, b) : fmaxf(a, b);
    float c1 = low128 ? fminf(c, d) : fmaxf(c, d);  // what lane tid^64 computes
    r[v] = low64 ? fminf(a1, c1) : fmaxf(a1, c1);
  }
}

template<int K>
__device__ __forceinline__ void bitonic_phase(float (&r)[V], int tid, float* buf) {
  const bool up = (tid & (K >> 4)) == 0;  // K=4096 -> always true
  if (K == 4096) lds_stage_4096(r, tid, buf);
  if (K == 2048) lds_stage64(r, tid, buf, up);
  constexpr int M0 = (K >> 5) < 32 ? (K >> 5) : 32;
#pragma unroll
  for (int m = M0; m >= 1; m >>= 1) shfl_stage(r, tid, m, up);
  reg_stage<8>(r, up);
  reg_stage<4>(r, up);
  reg_stage<2>(r, up);
  reg_stage<1>(r, up);
}

__device__ __forceinline__ void sort16_local(float (&r)[V], int tid) {
  reg_stage_static<2, 1>(r);
  reg_stage_static<4, 2>(r);
  reg_stage_static<4, 1>(r);
  reg_stage_static<8, 4>(r);
  reg_stage_static<8, 2>(r);
  reg_stage_static<8, 1>(r);
  const bool up16 = (tid & 1) == 0;  // i & 16 with i = tid*16+v
  reg_stage<8>(r, up16);
  reg_stage<4>(r, up16);
  reg_stage<2>(r, up16);
  reg_stage<1>(r, up16);
}

// load 16 consecutive points (48 floats = 12 float4) and project onto theta
__device__ __forceinline__ void load_project(const float* __restrict__ base, int tid,
                                             float t0, float t1, float t2,
                                             float (&r)[V]) {
  const float4* p4 = (const float4*)(base + (size_t)tid * 48);
#pragma unroll
  for (int g = 0; g < 4; ++g) {
    float4 A = p4[3 * g + 0];
    float4 B = p4[3 * g + 1];
    float4 C = p4[3 * g + 2];
    r[4 * g + 0] = A.x * t0 + A.y * t1 + A.z * t2;
    r[4 * g + 1] = A.w * t0 + B.x * t1 + B.y * t2;
    r[4 * g + 2] = B.z * t0 + B.w * t1 + C.x * t2;
    r[4 * g + 3] = C.y * t0 + C.z * t1 + C.w * t2;
  }
}

// ---------------- Kernel B: project + register bitonic sort + diff² --------
__global__ __launch_bounds__(BT) void dist_kernel(const float* __restrict__ x,
                                                  const float* __restrict__ y,
                                                  const float* __restrict__ theta,
                                                  float* __restrict__ dist) {
  __shared__ float buf[NP];  // 16 KB, slot-major exchange buffer

  const int bid = blockIdx.x;
  const int l = bid & (NL - 1);
  const int b = bid >> 7;
  const int tid = threadIdx.x;

  const float* tp = theta + ((size_t)l * NB + b) * 3;
  const float t0 = tp[0];
  const float t1 = tp[1];
  const float t2 = tp[2];

  float rx[V], ry[V];
  load_project(x + (size_t)b * NP * ND, tid, t0, t1, t2, rx);
  load_project(y + (size_t)b * NP * ND, tid, t0, t1, t2, ry);

  sort16_local(rx, tid);
  sort16_local(ry, tid);

  bitonic_phase<32>(rx, tid, buf);    bitonic_phase<32>(ry, tid, buf);
  bitonic_phase<64>(rx, tid, buf);    bitonic_phase<64>(ry, tid, buf);
  bitonic_phase<128>(rx, tid, buf);   bitonic_phase<128>(ry, tid, buf);
  bitonic_phase<256>(rx, tid, buf);   bitonic_phase<256>(ry, tid, buf);
  bitonic_phase<512>(rx, tid, buf);   bitonic_phase<512>(ry, tid, buf);
  bitonic_phase<1024>(rx, tid, buf);  bitonic_phase<1024>(ry, tid, buf);
  bitonic_phase<2048>(rx, tid, buf);  bitonic_phase<2048>(ry, tid, buf);
  bitonic_phase<4096>(rx, tid, buf);  bitonic_phase<4096>(ry, tid, buf);

  float s = 0.0f;
#pragma unroll
  for (int v = 0; v < V; ++v) {
    float d = rx[v] - ry[v];
    s = fmaf(d, d, s);
  }
  for (int off = 32; off; off >>= 1) s += __shfl_down(s, off, 64);
  __syncthreads();  // buf still owned by the last sort reads
  if ((tid & 63) == 0) buf[tid >> 6] = s;
  __syncthreads();
  if (tid == 0) {
    float tot = 0.0f;
    for (int w = 0; w < BT / 64; ++w) tot += buf[w];
    dist[l * NB + b] = tot;
  }
}

// ---------------- Kernel C: IMH chain + loss reduction ----------------
__global__ __launch_bounds__(64) void chain_kernel(const float* __restrict__ dist,
                                                   const float* __restrict__ logu,
                                                   float* __restrict__ out) {
  const int b = threadIdx.x;
  float dold = dist[b];  // l = 0
  float sum = dold;
  for (int l = 1; l < NL; ++l) {
    float dn = dist[l * NB + b];
    float acc = fminf(0.0f, dn - dold);
    if (logu[l * NB + b] <= acc) dold = dn;
    sum += dold;
  }
  float v = sqrtf(sum * (1.0f / (float)NL));
  for (int off = 32; off; off >>= 1) v += __shfl_down(v, off, 64);
  if (b == 0) out[0] = v * (1.0f / (float)NB);
}

extern "C" void kernel_launch(void* const* d_in, const int* in_sizes, int n_in,
                              void* d_out, int out_size, void* d_ws, size_t ws_size,
                              hipStream_t stream) {
  const float* x = (const float*)d_in[0];
  const float* y = (const float*)d_in[1];
  float* out = (float*)d_out;

  float* theta = (float*)d_ws;              // NL*NB*3 floats
  float* logu = theta + NL * NB * 3;        // NL*NB floats
  float* dist = logu + NL * NB;             // NL*NB floats

  hipLaunchKernelGGL(rng_kernel, dim3(NL), dim3(128), 0, stream, theta, logu);
  hipLaunchKernelGGL(dist_kernel, dim3(NB * NL), dim3(BT), 0, stream, x, y, theta, dist);
  hipLaunchKernelGGL(chain_kernel, dim3(1), dim3(64), 0, stream, dist, logu, out);
}

// Round 4
// 293.200 us; speedup vs baseline: 3.7547x; 1.6630x over previous
//
#include <hip/hip_runtime.h>
#include <stdint.h>

#define NB 64     // batch
#define NP 4096   // points per batch
#define ND 3      // dim
#define NL 128    // chain length / projections
#define BT 256    // block threads for dist kernel
#define W8 8      // f16x2 packs per thread per array (16 elems)

typedef uint32_t u32;
typedef _Float16 half2v __attribute__((ext_vector_type(2)));

// ---------------- JAX threefry2x32 (20 rounds) ----------------
__device__ __forceinline__ uint32_t rotl32(uint32_t v, int r) {
  return (v << r) | (v >> (32 - r));
}

__device__ __forceinline__ void threefry2x32(uint32_t k0, uint32_t k1,
                                             uint32_t c0, uint32_t c1,
                                             uint32_t& o0, uint32_t& o1) {
  uint32_t ks2 = k0 ^ k1 ^ 0x1BD11BDAu;
  uint32_t x0 = c0 + k0;
  uint32_t x1 = c1 + k1;
#define TF_RND(R) { x0 += x1; x1 = rotl32(x1, (R)); x1 ^= x0; }
  TF_RND(13) TF_RND(15) TF_RND(26) TF_RND(6)
  x0 += k1;  x1 += ks2 + 1u;
  TF_RND(17) TF_RND(29) TF_RND(16) TF_RND(24)
  x0 += ks2; x1 += k0 + 2u;
  TF_RND(13) TF_RND(15) TF_RND(26) TF_RND(6)
  x0 += k0;  x1 += k1 + 3u;
  TF_RND(17) TF_RND(29) TF_RND(16) TF_RND(24)
  x0 += k1;  x1 += ks2 + 4u;
  TF_RND(13) TF_RND(15) TF_RND(26) TF_RND(6)
  x0 += ks2; x1 += k0 + 5u;
#undef TF_RND
  o0 = x0; o1 = x1;
}

// ---------------- XLA ErfInv32 ----------------
__device__ __forceinline__ float erfinv_f(float x) {
  float w = -log1pf(-x * x);
  float p;
  if (w < 5.0f) {
    w = w - 2.5f;
    p = 2.81022636e-08f;
    p = fmaf(p, w, 3.43273939e-07f);
    p = fmaf(p, w, -3.5233877e-06f);
    p = fmaf(p, w, -4.39150654e-06f);
    p = fmaf(p, w, 0.00021858087f);
    p = fmaf(p, w, -0.00125372503f);
    p = fmaf(p, w, -0.00417768164f);
    p = fmaf(p, w, 0.246640727f);
    p = fmaf(p, w, 1.50140941f);
  } else {
    w = sqrtf(w) - 3.0f;
    p = -0.000200214257f;
    p = fmaf(p, w, 0.000100950558f);
    p = fmaf(p, w, 0.00134934322f);
    p = fmaf(p, w, -0.00367342844f);
    p = fmaf(p, w, 0.00573950773f);
    p = fmaf(p, w, -0.0076224613f);
    p = fmaf(p, w, 0.00943887047f);
    p = fmaf(p, w, 1.00167406f);
    p = fmaf(p, w, 2.83297682f);
  }
  return p * x;
}

__device__ __forceinline__ float bits_to_normal(uint32_t bits) {
  float f = __uint_as_float((bits >> 9) | 0x3F800000u) - 1.0f;  // [0,1)
  const float LO = -0.99999994f;  // nextafter(-1, 0)
  float u = fmaf(f, 2.0f, LO);
  u = fmaxf(LO, u);
  return 1.41421354f * erfinv_f(u);
}

__device__ __forceinline__ float bits_to_unif01(uint32_t bits) {
  float f = __uint_as_float((bits >> 9) | 0x3F800000u) - 1.0f;
  return fmaxf(0.0f, f);
}

// ---------------- Kernel A: thetas (normalized) + log-uniforms ----------
__global__ __launch_bounds__(128) void rng_kernel(float* __restrict__ theta,
                                                  float* __restrict__ logu) {
  const int l = blockIdx.x;
  const int tid = threadIdx.x;

  uint32_t kl0, kl1;
  threefry2x32(0u, 42u, 0u, (uint32_t)l, kl0, kl1);

  uint32_t na0 = kl0, na1 = kl1;
  uint32_t nb0 = 0u, nb1 = 0u;
  if (l > 0) {
    uint32_t a0, b0, a1, b1;
    threefry2x32(kl0, kl1, 0u, 2u, a0, b0);
    threefry2x32(kl0, kl1, 1u, 3u, a1, b1);
    na0 = a0; na1 = a1;
    nb0 = b0; nb1 = b1;
  }

  __shared__ float vals[NB * ND];
  if (tid < 96) {
    uint32_t o0, o1;
    threefry2x32(na0, na1, (uint32_t)tid, (uint32_t)(96 + tid), o0, o1);
    vals[tid] = bits_to_normal(o0);
    vals[96 + tid] = bits_to_normal(o1);
  }
  __syncthreads();

  if (tid < NB) {
    float v0 = vals[tid * 3 + 0];
    float v1 = vals[tid * 3 + 1];
    float v2 = vals[tid * 3 + 2];
    float s = sqrtf(v0 * v0 + v1 * v1 + v2 * v2);
    float* tp = theta + ((size_t)l * NB + tid) * 3;
    tp[0] = v0 / s;
    tp[1] = v1 / s;
    tp[2] = v2 / s;
  }

  if (l > 0 && tid < 32) {
    uint32_t o0, o1;
    threefry2x32(nb0, nb1, (uint32_t)tid, (uint32_t)(32 + tid), o0, o1);
    logu[l * NB + tid] = logf(bits_to_unif01(o0));
    logu[l * NB + 32 + tid] = logf(bits_to_unif01(o1));
  }
}

// ---------------- packed f16 compare-exchange primitives ----------------
__device__ __forceinline__ u32 pkmin(u32 a, u32 b) {
  u32 d; asm("v_pk_min_f16 %0, %1, %2" : "=v"(d) : "v"(a), "v"(b)); return d;
}
__device__ __forceinline__ u32 pkmax(u32 a, u32 b) {
  u32 d; asm("v_pk_max_f16 %0, %1, %2" : "=v"(d) : "v"(a), "v"(b)); return d;
}

// in-pack (element distance 1) CE, compile-time direction
template<bool ASC>
__device__ __forceinline__ void ip_s(u32& v) {
  u32 s = __builtin_amdgcn_alignbit(v, v, 16);  // swap halves
  u32 mn = pkmin(v, s), mx = pkmax(v, s);
  // asc: lo from mn, hi from mx  (perm sel<4 -> src1, >=4 -> src0)
  v = ASC ? __builtin_amdgcn_perm(mx, mn, 0x07060100u)
          : __builtin_amdgcn_perm(mn, mx, 0x07060100u);
}

// in-pack CE, runtime direction
__device__ __forceinline__ void ip_rt(u32& v, bool up) {
  u32 s = __builtin_amdgcn_alignbit(v, v, 16);
  u32 mn = pkmin(v, s), mx = pkmax(v, s);
  u32 hiSrc = up ? mx : mn;
  u32 loSrc = up ? mn : mx;
  v = __builtin_amdgcn_perm(hiSrc, loSrc, 0x07060100u);
}

// pack-pair CE, compile-time direction
template<bool ASC>
__device__ __forceinline__ void ce_s(u32& a, u32& b) {
  u32 mn = pkmin(a, b), mx = pkmax(a, b);
  a = ASC ? mn : mx;
  b = ASC ? mx : mn;
}

// pack-pair CE, runtime direction
__device__ __forceinline__ void ce_rt(u32& a, u32& b, bool up) {
  u32 mn = pkmin(a, b), mx = pkmax(a, b);
  u32 na = up ? mn : mx;
  u32 nb = up ? mx : mn;
  a = na; b = nb;
}

// cross-lane CE via shuffle of the whole pack
__device__ __forceinline__ void ce_shfl(u32& a, int m, bool keepmin) {
  u32 p = (u32)__shfl_xor((int)a, m, 64);
  u32 mn = pkmin(a, p), mx = pkmax(a, p);
  a = keepmin ? mn : mx;
}

// ---------------- sort of 16 in-thread elements (phases k=2..16) ---------
__device__ __forceinline__ void sort16_packed(u32 (&h)[2][W8], int tid) {
#pragma unroll
  for (int a = 0; a < 2; ++a) {
    // k=2 (dir from i&2 = w bit0)
    ip_s<true >(h[a][0]); ip_s<false>(h[a][1]);
    ip_s<true >(h[a][2]); ip_s<false>(h[a][3]);
    ip_s<true >(h[a][4]); ip_s<false>(h[a][5]);
    ip_s<true >(h[a][6]); ip_s<false>(h[a][7]);
    // k=4 (dir from i&4 = w bit1)
    ce_s<true >(h[a][0], h[a][1]); ce_s<false>(h[a][2], h[a][3]);
    ce_s<true >(h[a][4], h[a][5]); ce_s<false>(h[a][6], h[a][7]);
    ip_s<true >(h[a][0]); ip_s<true >(h[a][1]);
    ip_s<false>(h[a][2]); ip_s<false>(h[a][3]);
    ip_s<true >(h[a][4]); ip_s<true >(h[a][5]);
    ip_s<false>(h[a][6]); ip_s<false>(h[a][7]);
    // k=8 (dir from i&8 = w bit2)
    ce_s<true >(h[a][0], h[a][2]); ce_s<true >(h[a][1], h[a][3]);
    ce_s<false>(h[a][4], h[a][6]); ce_s<false>(h[a][5], h[a][7]);
    ce_s<true >(h[a][0], h[a][1]); ce_s<true >(h[a][2], h[a][3]);
    ce_s<false>(h[a][4], h[a][5]); ce_s<false>(h[a][6], h[a][7]);
    ip_s<true >(h[a][0]); ip_s<true >(h[a][1]);
    ip_s<true >(h[a][2]); ip_s<true >(h[a][3]);
    ip_s<false>(h[a][4]); ip_s<false>(h[a][5]);
    ip_s<false>(h[a][6]); ip_s<false>(h[a][7]);
  }
  // k=16 (dir from i&16 = tid bit0), stages j=8,4,2,1
  const bool up = (tid & 1) == 0;
#pragma unroll
  for (int a = 0; a < 2; ++a) {
    ce_rt(h[a][0], h[a][4], up); ce_rt(h[a][1], h[a][5], up);
    ce_rt(h[a][2], h[a][6], up); ce_rt(h[a][3], h[a][7], up);
    ce_rt(h[a][0], h[a][2], up); ce_rt(h[a][1], h[a][3], up);
    ce_rt(h[a][4], h[a][6], up); ce_rt(h[a][5], h[a][7], up);
    ce_rt(h[a][0], h[a][1], up); ce_rt(h[a][2], h[a][3], up);
    ce_rt(h[a][4], h[a][5], up); ce_rt(h[a][6], h[a][7], up);
    ip_rt(h[a][0], up); ip_rt(h[a][1], up); ip_rt(h[a][2], up); ip_rt(h[a][3], up);
    ip_rt(h[a][4], up); ip_rt(h[a][5], up); ip_rt(h[a][6], up); ip_rt(h[a][7], up);
  }
}

// in-thread tail of every phase k>=32: stages j=8,4,2,1
__device__ __forceinline__ void tail_reg(u32 (&h)[2][W8], bool up) {
#pragma unroll
  for (int a = 0; a < 2; ++a) {
    ce_rt(h[a][0], h[a][4], up); ce_rt(h[a][1], h[a][5], up);
    ce_rt(h[a][2], h[a][6], up); ce_rt(h[a][3], h[a][7], up);
    ce_rt(h[a][0], h[a][2], up); ce_rt(h[a][1], h[a][3], up);
    ce_rt(h[a][4], h[a][6], up); ce_rt(h[a][5], h[a][7], up);
    ce_rt(h[a][0], h[a][1], up); ce_rt(h[a][2], h[a][3], up);
    ce_rt(h[a][4], h[a][5], up); ce_rt(h[a][6], h[a][7], up);
    ip_rt(h[a][0], up); ip_rt(h[a][1], up); ip_rt(h[a][2], up); ip_rt(h[a][3], up);
    ip_rt(h[a][4], up); ip_rt(h[a][5], up); ip_rt(h[a][6], up); ip_rt(h[a][7], up);
  }
}

// phases k=32..1024: shuffle stages (j=k/2..16) + in-thread tail
template<int K>
__device__ __forceinline__ void phaseK(u32 (&h)[2][W8], int tid) {
  const bool up = (tid & (K >> 4)) == 0;
#pragma unroll
  for (int m = K / 32; m >= 1; m >>= 1) {
    const bool keepmin = (((tid & m) == 0) == up);
#pragma unroll
    for (int a = 0; a < 2; ++a)
#pragma unroll
      for (int w = 0; w < W8; ++w) ce_shfl(h[a][w], m, keepmin);
  }
  tail_reg(h, up);
}

// phase k=2048: one LDS exchange (tid^64) + shuffles + tail
__device__ __forceinline__ void phase2048(u32 (&h)[2][W8], int tid, u32* buf) {
  const bool up = (tid & 128) == 0;
  __syncthreads();
#pragma unroll
  for (int a = 0; a < 2; ++a)
#pragma unroll
    for (int w = 0; w < W8; ++w) buf[a * (NP / 2) + w * BT + tid] = h[a][w];
  __syncthreads();
  const bool km64 = (((tid & 64) == 0) == up);
#pragma unroll
  for (int a = 0; a < 2; ++a)
#pragma unroll
    for (int w = 0; w < W8; ++w) {
      u32 p = buf[a * (NP / 2) + w * BT + (tid ^ 64)];
      u32 mn = pkmin(h[a][w], p), mx = pkmax(h[a][w], p);
      h[a][w] = km64 ? mn : mx;
    }
#pragma unroll
  for (int m = 32; m >= 1; m >>= 1) {
    const bool keepmin = (((tid & m) == 0) == up);
#pragma unroll
    for (int a = 0; a < 2; ++a)
#pragma unroll
      for (int w = 0; w < W8; ++w) ce_shfl(h[a][w], m, keepmin);
  }
  tail_reg(h, up);
}

// phase k=4096 (up = true): fused j=2048 + j=1024 LDS stages, then shuffles, tail
__device__ __forceinline__ void phase4096(u32 (&h)[2][W8], int tid, u32* buf) {
  __syncthreads();
#pragma unroll
  for (int a = 0; a < 2; ++a)
#pragma unroll
    for (int w = 0; w < W8; ++w) buf[a * (NP / 2) + w * BT + tid] = h[a][w];
  __syncthreads();
  const bool low128 = (tid & 128) == 0;
  const bool low64 = (tid & 64) == 0;
#pragma unroll
  for (int a = 0; a < 2; ++a)
#pragma unroll
    for (int w = 0; w < W8; ++w) {
      u32 av = h[a][w];
      u32 bv = buf[a * (NP / 2) + w * BT + (tid ^ 128)];
      u32 cv = buf[a * (NP / 2) + w * BT + (tid ^ 64)];
      u32 dv = buf[a * (NP / 2) + w * BT + (tid ^ 192)];
      u32 a1 = low128 ? pkmin(av, bv) : pkmax(av, bv);
      u32 c1 = low128 ? pkmin(cv, dv) : pkmax(cv, dv);  // partner lane's j=2048 result
      h[a][w] = low64 ? pkmin(a1, c1) : pkmax(a1, c1);
    }
#pragma unroll
  for (int m = 32; m >= 1; m >>= 1) {
    const bool keepmin = (tid & m) == 0;
#pragma unroll
    for (int a = 0; a < 2; ++a)
#pragma unroll
      for (int w = 0; w < W8; ++w) ce_shfl(h[a][w], m, keepmin);
  }
  tail_reg(h, true);
}

// load 16 consecutive points, project, pack to 8 f16x2 regs
__device__ __forceinline__ void load_project_pack(const float* __restrict__ base, int tid,
                                                  float t0, float t1, float t2,
                                                  u32 (&h)[W8]) {
  const float4* p4 = (const float4*)(base + (size_t)tid * 48);
#pragma unroll
  for (int g = 0; g < 4; ++g) {
    float4 A = p4[3 * g + 0];
    float4 B = p4[3 * g + 1];
    float4 C = p4[3 * g + 2];
    float r0 = A.x * t0 + A.y * t1 + A.z * t2;
    float r1 = A.w * t0 + B.x * t1 + B.y * t2;
    float r2 = B.z * t0 + B.w * t1 + C.x * t2;
    float r3 = C.y * t0 + C.z * t1 + C.w * t2;
    h[2 * g + 0] = __builtin_bit_cast(u32, __builtin_amdgcn_cvt_pkrtz(r0, r1));
    h[2 * g + 1] = __builtin_bit_cast(u32, __builtin_amdgcn_cvt_pkrtz(r2, r3));
  }
}

// ---------------- Kernel B: project + packed-f16 bitonic sort + diff² -----
__global__ __launch_bounds__(BT) void dist_kernel(const float* __restrict__ x,
                                                  const float* __restrict__ y,
                                                  const float* __restrict__ theta,
                                                  float* __restrict__ dist) {
  __shared__ u32 buf[NP];        // 16 KB: both arrays' exchange slots
  __shared__ float red[BT / 64];

  const int bid = blockIdx.x;
  const int l = bid & (NL - 1);
  const int b = bid >> 7;
  const int tid = threadIdx.x;

  const float* tp = theta + ((size_t)l * NB + b) * 3;
  const float t0 = tp[0];
  const float t1 = tp[1];
  const float t2 = tp[2];

  u32 h[2][W8];
  load_project_pack(x + (size_t)b * NP * ND, tid, t0, t1, t2, h[0]);
  load_project_pack(y + (size_t)b * NP * ND, tid, t0, t1, t2, h[1]);

  sort16_packed(h, tid);
  phaseK<32>(h, tid);
  phaseK<64>(h, tid);
  phaseK<128>(h, tid);
  phaseK<256>(h, tid);
  phaseK<512>(h, tid);
  phaseK<1024>(h, tid);
  phase2048(h, tid, buf);
  phase4096(h, tid, buf);

  float s = 0.0f;
#pragma unroll
  for (int w = 0; w < W8; ++w) {
    half2v hx = __builtin_bit_cast(half2v, h[0][w]);
    half2v hy = __builtin_bit_cast(half2v, h[1][w]);
    float d0 = (float)hx[0] - (float)hy[0];
    float d1 = (float)hx[1] - (float)hy[1];
    s = fmaf(d0, d0, s);
    s = fmaf(d1, d1, s);
  }
  for (int off = 32; off; off >>= 1) s += __shfl_down(s, off, 64);
  if ((tid & 63) == 0) red[tid >> 6] = s;
  __syncthreads();
  if (tid == 0) {
    dist[l * NB + b] = red[0] + red[1] + red[2] + red[3];
  }
}

// ---------------- Kernel C: IMH chain + loss reduction ----------------
__global__ __launch_bounds__(64) void chain_kernel(const float* __restrict__ dist,
                                                   const float* __restrict__ logu,
                                                   float* __restrict__ out) {
  const int b = threadIdx.x;
  float dold = dist[b];  // l = 0
  float sum = dold;
  for (int l = 1; l < NL; ++l) {
    float dn = dist[l * NB + b];
    float acc = fminf(0.0f, dn - dold);
    if (logu[l * NB + b] <= acc) dold = dn;
    sum += dold;
  }
  float v = sqrtf(sum * (1.0f / (float)NL));
  for (int off = 32; off; off >>= 1) v += __shfl_down(v, off, 64);
  if (b == 0) out[0] = v * (1.0f / (float)NB);
}

extern "C" void kernel_launch(void* const* d_in, const int* in_sizes, int n_in,
                              void* d_out, int out_size, void* d_ws, size_t ws_size,
                              hipStream_t stream) {
  const float* x = (const float*)d_in[0];
  const float* y = (const float*)d_in[1];
  float* out = (float*)d_out;

  float* theta = (float*)d_ws;              // NL*NB*3 floats
  float* logu = theta + NL * NB * 3;        // NL*NB floats
  float* dist = logu + NL * NB;             // NL*NB floats

  hipLaunchKernelGGL(rng_kernel, dim3(NL), dim3(128), 0, stream, theta, logu);
  hipLaunchKernelGGL(dist_kernel, dim3(NB * NL), dim3(BT), 0, stream, x, y, theta, dist);
  hipLaunchKernelGGL(chain_kernel, dim3(1), dim3(64), 0, stream, dist, logu, out);
}

// Round 5
// 277.078 us; speedup vs baseline: 3.9732x; 1.0582x over previous
//
#include <hip/hip_runtime.h>
#include <stdint.h>

#define NB 64     // batch
#define NP 4096   // points per batch
#define ND 3      // dim
#define NL 128    // chain length / projections
#define BT 256    // block threads for dist kernel
#define NR 16     // u32 regs per thread; reg v = (x_i in lo16, y_i in hi16), i = tid*16+v

typedef uint32_t u32;
typedef _Float16 half2v __attribute__((ext_vector_type(2)));

// ---------------- JAX threefry2x32 (20 rounds) ----------------
__device__ __forceinline__ uint32_t rotl32(uint32_t v, int r) {
  return (v << r) | (v >> (32 - r));
}

__device__ __forceinline__ void threefry2x32(uint32_t k0, uint32_t k1,
                                             uint32_t c0, uint32_t c1,
                                             uint32_t& o0, uint32_t& o1) {
  uint32_t ks2 = k0 ^ k1 ^ 0x1BD11BDAu;
  uint32_t x0 = c0 + k0;
  uint32_t x1 = c1 + k1;
#define TF_RND(R) { x0 += x1; x1 = rotl32(x1, (R)); x1 ^= x0; }
  TF_RND(13) TF_RND(15) TF_RND(26) TF_RND(6)
  x0 += k1;  x1 += ks2 + 1u;
  TF_RND(17) TF_RND(29) TF_RND(16) TF_RND(24)
  x0 += ks2; x1 += k0 + 2u;
  TF_RND(13) TF_RND(15) TF_RND(26) TF_RND(6)
  x0 += k0;  x1 += k1 + 3u;
  TF_RND(17) TF_RND(29) TF_RND(16) TF_RND(24)
  x0 += k1;  x1 += ks2 + 4u;
  TF_RND(13) TF_RND(15) TF_RND(26) TF_RND(6)
  x0 += ks2; x1 += k0 + 5u;
#undef TF_RND
  o0 = x0; o1 = x1;
}

// ---------------- XLA ErfInv32 ----------------
__device__ __forceinline__ float erfinv_f(float x) {
  float w = -log1pf(-x * x);
  float p;
  if (w < 5.0f) {
    w = w - 2.5f;
    p = 2.81022636e-08f;
    p = fmaf(p, w, 3.43273939e-07f);
    p = fmaf(p, w, -3.5233877e-06f);
    p = fmaf(p, w, -4.39150654e-06f);
    p = fmaf(p, w, 0.00021858087f);
    p = fmaf(p, w, -0.00125372503f);
    p = fmaf(p, w, -0.00417768164f);
    p = fmaf(p, w, 0.246640727f);
    p = fmaf(p, w, 1.50140941f);
  } else {
    w = sqrtf(w) - 3.0f;
    p = -0.000200214257f;
    p = fmaf(p, w, 0.000100950558f);
    p = fmaf(p, w, 0.00134934322f);
    p = fmaf(p, w, -0.00367342844f);
    p = fmaf(p, w, 0.00573950773f);
    p = fmaf(p, w, -0.0076224613f);
    p = fmaf(p, w, 0.00943887047f);
    p = fmaf(p, w, 1.00167406f);
    p = fmaf(p, w, 2.83297682f);
  }
  return p * x;
}

__device__ __forceinline__ float bits_to_normal(uint32_t bits) {
  float f = __uint_as_float((bits >> 9) | 0x3F800000u) - 1.0f;  // [0,1)
  const float LO = -0.99999994f;  // nextafter(-1, 0)
  float u = fmaf(f, 2.0f, LO);
  u = fmaxf(LO, u);
  return 1.41421354f * erfinv_f(u);
}

__device__ __forceinline__ float bits_to_unif01(uint32_t bits) {
  float f = __uint_as_float((bits >> 9) | 0x3F800000u) - 1.0f;
  return fmaxf(0.0f, f);
}

// ---------------- Kernel A: thetas (normalized) + log-uniforms ----------
__global__ __launch_bounds__(128) void rng_kernel(float* __restrict__ theta,
                                                  float* __restrict__ logu) {
  const int l = blockIdx.x;
  const int tid = threadIdx.x;

  uint32_t kl0, kl1;
  threefry2x32(0u, 42u, 0u, (uint32_t)l, kl0, kl1);

  uint32_t na0 = kl0, na1 = kl1;
  uint32_t nb0 = 0u, nb1 = 0u;
  if (l > 0) {
    uint32_t a0, b0, a1, b1;
    threefry2x32(kl0, kl1, 0u, 2u, a0, b0);
    threefry2x32(kl0, kl1, 1u, 3u, a1, b1);
    na0 = a0; na1 = a1;
    nb0 = b0; nb1 = b1;
  }

  __shared__ float vals[NB * ND];
  if (tid < 96) {
    uint32_t o0, o1;
    threefry2x32(na0, na1, (uint32_t)tid, (uint32_t)(96 + tid), o0, o1);
    vals[tid] = bits_to_normal(o0);
    vals[96 + tid] = bits_to_normal(o1);
  }
  __syncthreads();

  if (tid < NB) {
    float v0 = vals[tid * 3 + 0];
    float v1 = vals[tid * 3 + 1];
    float v2 = vals[tid * 3 + 2];
    float s = sqrtf(v0 * v0 + v1 * v1 + v2 * v2);
    float* tp = theta + ((size_t)l * NB + tid) * 3;
    tp[0] = v0 / s;
    tp[1] = v1 / s;
    tp[2] = v2 / s;
  }

  if (l > 0 && tid < 32) {
    uint32_t o0, o1;
    threefry2x32(nb0, nb1, (uint32_t)tid, (uint32_t)(32 + tid), o0, o1);
    logu[l * NB + tid] = logf(bits_to_unif01(o0));
    logu[l * NB + 32 + tid] = logf(bits_to_unif01(o1));
  }
}

// ---------------- packed primitives ----------------
__device__ __forceinline__ u32 pkmin(u32 a, u32 b) {
  u32 d; asm("v_pk_min_f16 %0, %1, %2" : "=v"(d) : "v"(a), "v"(b)); return d;
}
__device__ __forceinline__ u32 pkmax(u32 a, u32 b) {
  u32 d; asm("v_pk_max_f16 %0, %1, %2" : "=v"(d) : "v"(a), "v"(b)); return d;
}

// static ascending / descending compare-exchange between regs
__device__ __forceinline__ void ceA(u32& a, u32& b) {
  u32 mn = pkmin(a, b), mx = pkmax(a, b); a = mn; b = mx;
}
__device__ __forceinline__ void ceD(u32& a, u32& b) {
  u32 mn = pkmin(a, b), mx = pkmax(a, b); a = mx; b = mn;
}

// sign flip (both halves) by per-thread mask
__device__ __forceinline__ void flipx(u32 (&r)[NR], u32 mask) {
#pragma unroll
  for (int w = 0; w < NR; ++w) r[w] ^= mask;
}
__device__ __forceinline__ u32 fmask(u32 d) {  // d in {0,1}
  return (d << 31) | (d << 15);
}

// in-thread tail of every phase (flip domain, all ascending): j = 8,4,2,1
__device__ __forceinline__ void tailA(u32 (&r)[NR]) {
#pragma unroll
  for (int v = 0; v < 8; ++v) ceA(r[v], r[v + 8]);
#pragma unroll
  for (int v = 0; v < NR; ++v) if (!(v & 4)) ceA(r[v], r[v | 4]);
#pragma unroll
  for (int v = 0; v < NR; ++v) if (!(v & 2)) ceA(r[v], r[v | 2]);
#pragma unroll
  for (int v = 0; v < NR; ++v) if (!(v & 1)) ceA(r[v], r[v | 1]);
}

// static phases k=2,4,8 (true domain; dir from element-index bits = v bits)
__device__ __forceinline__ void sort_k2_8(u32 (&r)[NR]) {
  // k=2, j=1 (dir = (v&2)==0)
  ceA(r[0], r[1]);  ceD(r[2], r[3]);  ceA(r[4], r[5]);  ceD(r[6], r[7]);
  ceA(r[8], r[9]);  ceD(r[10], r[11]); ceA(r[12], r[13]); ceD(r[14], r[15]);
  // k=4, j=2 (dir = (v&4)==0)
  ceA(r[0], r[2]);  ceA(r[1], r[3]);  ceD(r[4], r[6]);  ceD(r[5], r[7]);
  ceA(r[8], r[10]); ceA(r[9], r[11]); ceD(r[12], r[14]); ceD(r[13], r[15]);
  // k=4, j=1
  ceA(r[0], r[1]);  ceA(r[2], r[3]);  ceD(r[4], r[5]);  ceD(r[6], r[7]);
  ceA(r[8], r[9]);  ceA(r[10], r[11]); ceD(r[12], r[13]); ceD(r[14], r[15]);
  // k=8, j=4 (dir = (v&8)==0)
  ceA(r[0], r[4]);  ceA(r[1], r[5]);  ceA(r[2], r[6]);  ceA(r[3], r[7]);
  ceD(r[8], r[12]); ceD(r[9], r[13]); ceD(r[10], r[14]); ceD(r[11], r[15]);
  // k=8, j=2
  ceA(r[0], r[2]);  ceA(r[1], r[3]);  ceA(r[4], r[6]);  ceA(r[5], r[7]);
  ceD(r[8], r[10]); ceD(r[9], r[11]); ceD(r[12], r[14]); ceD(r[13], r[15]);
  // k=8, j=1
  ceA(r[0], r[1]);  ceA(r[2], r[3]);  ceA(r[4], r[5]);  ceA(r[6], r[7]);
  ceD(r[8], r[9]);  ceD(r[10], r[11]); ceD(r[12], r[13]); ceD(r[14], r[15]);
}

// cross-lane stage: partner lane = lane ^ m (m = 1..32), flip domain
__device__ __forceinline__ void stage_x(u32 (&r)[NR], int lanesh2, int m, bool km) {
  const int addr = lanesh2 ^ (m << 2);
  u32 p[NR];
#pragma unroll
  for (int w = 0; w < NR; ++w)
    p[w] = (u32)__builtin_amdgcn_ds_bpermute(addr, (int)r[w]);
#pragma unroll
  for (int w = 0; w < NR; ++w) {
    u32 mn = pkmin(r[w], p[w]), mx = pkmax(r[w], p[w]);
    r[w] = km ? mn : mx;
  }
}

// shuffle stages m = MB..1 (j = 16*MB..16) + in-thread tail
template<int MB>
__device__ __forceinline__ void phase_sh(u32 (&r)[NR], int lanesh2, int tid) {
#pragma unroll
  for (int m = MB; m >= 1; m >>= 1) stage_x(r, lanesh2, m, (tid & m) == 0);
  tailA(r);
}

// ---------------- Kernel B: project + xy-packed flip-domain bitonic ------
__global__ __launch_bounds__(BT) void dist_kernel(const float* __restrict__ x,
                                                  const float* __restrict__ y,
                                                  const float* __restrict__ theta,
                                                  float* __restrict__ dist) {
  __shared__ u32 buf[NP];  // 16 KB slot-major exchange buffer

  const int bid = blockIdx.x;
  const int l = bid & (NL - 1);
  const int b = bid >> 7;
  const int tid = threadIdx.x;

  const float* tp = theta + ((size_t)l * NB + b) * 3;
  const float t0 = tp[0];
  const float t1 = tp[1];
  const float t2 = tp[2];

  u32 r[NR];
  {
    const float4* px = (const float4*)(x + (size_t)b * NP * ND + (size_t)tid * 48);
    const float4* py = (const float4*)(y + (size_t)b * NP * ND + (size_t)tid * 48);
#pragma unroll
    for (int g = 0; g < 4; ++g) {
      float4 XA = px[3 * g], XB = px[3 * g + 1], XC = px[3 * g + 2];
      float4 YA = py[3 * g], YB = py[3 * g + 1], YC = py[3 * g + 2];
      float x0 = XA.x * t0 + XA.y * t1 + XA.z * t2;
      float x1 = XA.w * t0 + XB.x * t1 + XB.y * t2;
      float x2 = XB.z * t0 + XB.w * t1 + XC.x * t2;
      float x3 = XC.y * t0 + XC.z * t1 + XC.w * t2;
      float y0 = YA.x * t0 + YA.y * t1 + YA.z * t2;
      float y1 = YA.w * t0 + YB.x * t1 + YB.y * t2;
      float y2 = YB.z * t0 + YB.w * t1 + YC.x * t2;
      float y3 = YC.y * t0 + YC.z * t1 + YC.w * t2;
      r[4 * g + 0] = __builtin_bit_cast(u32, __builtin_amdgcn_cvt_pkrtz(x0, y0));
      r[4 * g + 1] = __builtin_bit_cast(u32, __builtin_amdgcn_cvt_pkrtz(x1, y1));
      r[4 * g + 2] = __builtin_bit_cast(u32, __builtin_amdgcn_cvt_pkrtz(x2, y2));
      r[4 * g + 3] = __builtin_bit_cast(u32, __builtin_amdgcn_cvt_pkrtz(x3, y3));
    }
  }

  sort_k2_8(r);
  const int lanesh2 = (tid & 63) << 2;

  // k=16 (flip bit: tid&1)
  flipx(r, fmask((u32)tid & 1u));
  tailA(r);
  // k=32 .. k=1024 (flip-delta = xor of adjacent tid bits)
  flipx(r, fmask(((u32)(tid >> 0) ^ (u32)(tid >> 1)) & 1u)); phase_sh<1>(r, lanesh2, tid);
  flipx(r, fmask(((u32)(tid >> 1) ^ (u32)(tid >> 2)) & 1u)); phase_sh<2>(r, lanesh2, tid);
  flipx(r, fmask(((u32)(tid >> 2) ^ (u32)(tid >> 3)) & 1u)); phase_sh<4>(r, lanesh2, tid);
  flipx(r, fmask(((u32)(tid >> 3) ^ (u32)(tid >> 4)) & 1u)); phase_sh<8>(r, lanesh2, tid);
  flipx(r, fmask(((u32)(tid >> 4) ^ (u32)(tid >> 5)) & 1u)); phase_sh<16>(r, lanesh2, tid);
  flipx(r, fmask(((u32)(tid >> 5) ^ (u32)(tid >> 6)) & 1u)); phase_sh<32>(r, lanesh2, tid);

  // k=2048: flip, LDS stage (tid^64), shuffles m=32..1, tail
  flipx(r, fmask(((u32)(tid >> 6) ^ (u32)(tid >> 7)) & 1u));
  __syncthreads();
#pragma unroll
  for (int w = 0; w < NR; ++w) buf[w * BT + tid] = r[w];
  __syncthreads();
  {
    const bool km = (tid & 64) == 0;
#pragma unroll
    for (int w = 0; w < NR; ++w) {
      u32 p = buf[w * BT + (tid ^ 64)];
      u32 mn = pkmin(r[w], p), mx = pkmax(r[w], p);
      r[w] = km ? mn : mx;
    }
  }
  phase_sh<32>(r, lanesh2, tid);

  // k=4096: unflip (bit7), fused LDS stages j=2048 (tid^128) + j=1024 (tid^64)
  flipx(r, fmask((u32)(tid >> 7) & 1u));
  __syncthreads();
#pragma unroll
  for (int w = 0; w < NR; ++w) buf[w * BT + tid] = r[w];
  __syncthreads();
  {
    const bool a128 = (tid & 128) == 0;
    const bool a64 = (tid & 64) == 0;
#pragma unroll
    for (int w = 0; w < NR; ++w) {
      u32 av = r[w];
      u32 bv = buf[w * BT + (tid ^ 128)];
      u32 cv = buf[w * BT + (tid ^ 64)];
      u32 dv = buf[w * BT + (tid ^ 192)];
      u32 a1 = a128 ? pkmin(av, bv) : pkmax(av, bv);
      u32 c1 = a128 ? pkmin(cv, dv) : pkmax(cv, dv);  // partner lane's j=2048 result
      r[w] = a64 ? pkmin(a1, c1) : pkmax(a1, c1);
    }
  }
  phase_sh<32>(r, lanesh2, tid);

  // epilogue: sum (xs_i - ys_i)^2 = (lo - hi)^2 per reg
  float s = 0.0f;
#pragma unroll
  for (int w = 0; w < NR; ++w) {
    half2v h = __builtin_bit_cast(half2v, r[w]);
    float d = (float)h[0] - (float)h[1];
    s = fmaf(d, d, s);
  }
  for (int off = 32; off; off >>= 1) s += __shfl_down(s, off, 64);
  __syncthreads();
  float* red = (float*)buf;
  if ((tid & 63) == 0) red[tid >> 6] = s;
  __syncthreads();
  if (tid == 0) dist[l * NB + b] = red[0] + red[1] + red[2] + red[3];
}

// ---------------- Kernel C: IMH chain + loss reduction ----------------
__global__ __launch_bounds__(64) void chain_kernel(const float* __restrict__ dist,
                                                   const float* __restrict__ logu,
                                                   float* __restrict__ out) {
  const int b = threadIdx.x;
  float dold = dist[b];  // l = 0
  float sum = dold;
  for (int l = 1; l < NL; ++l) {
    float dn = dist[l * NB + b];
    float acc = fminf(0.0f, dn - dold);
    if (logu[l * NB + b] <= acc) dold = dn;
    sum += dold;
  }
  float v = sqrtf(sum * (1.0f / (float)NL));
  for (int off = 32; off; off >>= 1) v += __shfl_down(v, off, 64);
  if (b == 0) out[0] = v * (1.0f / (float)NB);
}

extern "C" void kernel_launch(void* const* d_in, const int* in_sizes, int n_in,
                              void* d_out, int out_size, void* d_ws, size_t ws_size,
                              hipStream_t stream) {
  const float* x = (const float*)d_in[0];
  const float* y = (const float*)d_in[1];
  float* out = (float*)d_out;

  float* theta = (float*)d_ws;              // NL*NB*3 floats
  float* logu = theta + NL * NB * 3;        // NL*NB floats
  float* dist = logu + NL * NB;             // NL*NB floats

  hipLaunchKernelGGL(rng_kernel, dim3(NL), dim3(128), 0, stream, theta, logu);
  hipLaunchKernelGGL(dist_kernel, dim3(NB * NL), dim3(BT), 0, stream, x, y, theta, dist);
  hipLaunchKernelGGL(chain_kernel, dim3(1), dim3(64), 0, stream, dist, logu, out);
}

// Round 8
// 269.608 us; speedup vs baseline: 4.0833x; 1.0277x over previous
//
#include <hip/hip_runtime.h>
#include <stdint.h>

#define NB 64     // batch
#define NP 4096   // points per batch
#define ND 3      // dim
#define NL 128    // chain length / projections
#define BT 256    // block threads for dist kernel
#define NR 16     // u32 regs per thread; reg v = (x_i in lo16, y_i in hi16), i = tid*16+v

typedef uint32_t u32;
typedef _Float16 half2v __attribute__((ext_vector_type(2)));

// ---------------- JAX threefry2x32 (20 rounds) ----------------
__device__ __forceinline__ uint32_t rotl32(uint32_t v, int r) {
  return (v << r) | (v >> (32 - r));
}

__device__ __forceinline__ void threefry2x32(uint32_t k0, uint32_t k1,
                                             uint32_t c0, uint32_t c1,
                                             uint32_t& o0, uint32_t& o1) {
  uint32_t ks2 = k0 ^ k1 ^ 0x1BD11BDAu;
  uint32_t x0 = c0 + k0;
  uint32_t x1 = c1 + k1;
#define TF_RND(R) { x0 += x1; x1 = rotl32(x1, (R)); x1 ^= x0; }
  TF_RND(13) TF_RND(15) TF_RND(26) TF_RND(6)
  x0 += k1;  x1 += ks2 + 1u;
  TF_RND(17) TF_RND(29) TF_RND(16) TF_RND(24)
  x0 += ks2; x1 += k0 + 2u;
  TF_RND(13) TF_RND(15) TF_RND(26) TF_RND(6)
  x0 += k0;  x1 += k1 + 3u;
  TF_RND(17) TF_RND(29) TF_RND(16) TF_RND(24)
  x0 += k1;  x1 += ks2 + 4u;
  TF_RND(13) TF_RND(15) TF_RND(26) TF_RND(6)
  x0 += ks2; x1 += k0 + 5u;
#undef TF_RND
  o0 = x0; o1 = x1;
}

// ---------------- XLA ErfInv32 ----------------
__device__ __forceinline__ float erfinv_f(float x) {
  float w = -log1pf(-x * x);
  float p;
  if (w < 5.0f) {
    w = w - 2.5f;
    p = 2.81022636e-08f;
    p = fmaf(p, w, 3.43273939e-07f);
    p = fmaf(p, w, -3.5233877e-06f);
    p = fmaf(p, w, -4.39150654e-06f);
    p = fmaf(p, w, 0.00021858087f);
    p = fmaf(p, w, -0.00125372503f);
    p = fmaf(p, w, -0.00417768164f);
    p = fmaf(p, w, 0.246640727f);
    p = fmaf(p, w, 1.50140941f);
  } else {
    w = sqrtf(w) - 3.0f;
    p = -0.000200214257f;
    p = fmaf(p, w, 0.000100950558f);
    p = fmaf(p, w, 0.00134934322f);
    p = fmaf(p, w, -0.00367342844f);
    p = fmaf(p, w, 0.00573950773f);
    p = fmaf(p, w, -0.0076224613f);
    p = fmaf(p, w, 0.00943887047f);
    p = fmaf(p, w, 1.00167406f);
    p = fmaf(p, w, 2.83297682f);
  }
  return p * x;
}

__device__ __forceinline__ float bits_to_normal(uint32_t bits) {
  float f = __uint_as_float((bits >> 9) | 0x3F800000u) - 1.0f;  // [0,1)
  const float LO = -0.99999994f;  // nextafter(-1, 0)
  float u = fmaf(f, 2.0f, LO);
  u = fmaxf(LO, u);
  return 1.41421354f * erfinv_f(u);
}

__device__ __forceinline__ float bits_to_unif01(uint32_t bits) {
  float f = __uint_as_float((bits >> 9) | 0x3F800000u) - 1.0f;
  return fmaxf(0.0f, f);
}

// ---------------- Kernel A: thetas (normalized) + log-uniforms ----------
__global__ __launch_bounds__(128) void rng_kernel(float* __restrict__ theta,
                                                  float* __restrict__ logu) {
  const int l = blockIdx.x;
  const int tid = threadIdx.x;

  uint32_t kl0, kl1;
  threefry2x32(0u, 42u, 0u, (uint32_t)l, kl0, kl1);

  uint32_t na0 = kl0, na1 = kl1;
  uint32_t nb0 = 0u, nb1 = 0u;
  if (l > 0) {
    uint32_t a0, b0, a1, b1;
    threefry2x32(kl0, kl1, 0u, 2u, a0, b0);
    threefry2x32(kl0, kl1, 1u, 3u, a1, b1);
    na0 = a0; na1 = a1;
    nb0 = b0; nb1 = b1;
  }

  __shared__ float vals[NB * ND];
  if (tid < 96) {
    uint32_t o0, o1;
    threefry2x32(na0, na1, (uint32_t)tid, (uint32_t)(96 + tid), o0, o1);
    vals[tid] = bits_to_normal(o0);
    vals[96 + tid] = bits_to_normal(o1);
  }
  __syncthreads();

  if (tid < NB) {
    float v0 = vals[tid * 3 + 0];
    float v1 = vals[tid * 3 + 1];
    float v2 = vals[tid * 3 + 2];
    float s = sqrtf(v0 * v0 + v1 * v1 + v2 * v2);
    float* tp = theta + ((size_t)l * NB + tid) * 3;
    tp[0] = v0 / s;
    tp[1] = v1 / s;
    tp[2] = v2 / s;
  }

  if (l > 0 && tid < 32) {
    uint32_t o0, o1;
    threefry2x32(nb0, nb1, (uint32_t)tid, (uint32_t)(32 + tid), o0, o1);
    logu[l * NB + tid] = logf(bits_to_unif01(o0));
    logu[l * NB + 32 + tid] = logf(bits_to_unif01(o1));
  }
}

// ---------------- packed primitives ----------------
__device__ __forceinline__ u32 pkmin(u32 a, u32 b) {
  u32 d; asm("v_pk_min_f16 %0, %1, %2" : "=v"(d) : "v"(a), "v"(b)); return d;
}
__device__ __forceinline__ u32 pkmax(u32 a, u32 b) {
  u32 d; asm("v_pk_max_f16 %0, %1, %2" : "=v"(d) : "v"(a), "v"(b)); return d;
}

// static ascending / descending compare-exchange between regs
__device__ __forceinline__ void ceA(u32& a, u32& b) {
  u32 mn = pkmin(a, b), mx = pkmax(a, b); a = mn; b = mx;
}
__device__ __forceinline__ void ceD(u32& a, u32& b) {
  u32 mn = pkmin(a, b), mx = pkmax(a, b); a = mx; b = mn;
}

// sign flip (both halves) by per-thread mask
__device__ __forceinline__ void flipx(u32 (&r)[NR], u32 mask) {
#pragma unroll
  for (int w = 0; w < NR; ++w) r[w] ^= mask;
}
__device__ __forceinline__ u32 fmask(u32 d) {  // d in {0,1}
  return (d << 31) | (d << 15);
}

// in-thread tail of every phase (flip domain, all ascending): j = 8,4,2,1
__device__ __forceinline__ void tailA(u32 (&r)[NR]) {
#pragma unroll
  for (int v = 0; v < 8; ++v) ceA(r[v], r[v + 8]);
#pragma unroll
  for (int v = 0; v < NR; ++v) if (!(v & 4)) ceA(r[v], r[v | 4]);
#pragma unroll
  for (int v = 0; v < NR; ++v) if (!(v & 2)) ceA(r[v], r[v | 2]);
#pragma unroll
  for (int v = 0; v < NR; ++v) if (!(v & 1)) ceA(r[v], r[v | 1]);
}

// static phases k=2,4,8 (true domain; dir from element-index bits = v bits)
__device__ __forceinline__ void sort_k2_8(u32 (&r)[NR]) {
  // k=2, j=1 (dir = (v&2)==0)
  ceA(r[0], r[1]);  ceD(r[2], r[3]);  ceA(r[4], r[5]);  ceD(r[6], r[7]);
  ceA(r[8], r[9]);  ceD(r[10], r[11]); ceA(r[12], r[13]); ceD(r[14], r[15]);
  // k=4, j=2 (dir = (v&4)==0)
  ceA(r[0], r[2]);  ceA(r[1], r[3]);  ceD(r[4], r[6]);  ceD(r[5], r[7]);
  ceA(r[8], r[10]); ceA(r[9], r[11]); ceD(r[12], r[14]); ceD(r[13], r[15]);
  // k=4, j=1
  ceA(r[0], r[1]);  ceA(r[2], r[3]);  ceD(r[4], r[5]);  ceD(r[6], r[7]);
  ceA(r[8], r[9]);  ceA(r[10], r[11]); ceD(r[12], r[13]); ceD(r[14], r[15]);
  // k=8, j=4 (dir = (v&8)==0)
  ceA(r[0], r[4]);  ceA(r[1], r[5]);  ceA(r[2], r[6]);  ceA(r[3], r[7]);
  ceD(r[8], r[12]); ceD(r[9], r[13]); ceD(r[10], r[14]); ceD(r[11], r[15]);
  // k=8, j=2
  ceA(r[0], r[2]);  ceA(r[1], r[3]);  ceA(r[4], r[6]);  ceA(r[5], r[7]);
  ceD(r[8], r[10]); ceD(r[9], r[11]); ceD(r[12], r[14]); ceD(r[13], r[15]);
  // k=8, j=1
  ceA(r[0], r[1]);  ceA(r[2], r[3]);  ceA(r[4], r[5]);  ceA(r[6], r[7]);
  ceD(r[8], r[9]);  ceD(r[10], r[11]); ceD(r[12], r[13]); ceD(r[14], r[15]);
}

// keep-min / keep-max select
__device__ __forceinline__ void ce_keep(u32& a, u32 p, bool km) {
  u32 mn = pkmin(a, p), mx = pkmax(a, p);
  a = km ? mn : mx;
}

// cross-lane stage (any m = 1..32): all 16 ds_bpermute issued in ONE asm
// block with a single s_waitcnt (single latency exposure per stage).
// Addresses lanesh2 ^ (m<<2) proven bit-exact in round 5; DS source-operand
// reads are hardware-scoreboarded (no manual hazard waits needed).
__device__ __forceinline__ void stage_bperm(u32 (&r)[NR], int addr, bool km) {
  u32 p0, p1, p2, p3, p4, p5, p6, p7, p8, p9, p10, p11, p12, p13, p14, p15;
  asm("ds_bpermute_b32 %0, %16, %17\n\t"
      "ds_bpermute_b32 %1, %16, %18\n\t"
      "ds_bpermute_b32 %2, %16, %19\n\t"
      "ds_bpermute_b32 %3, %16, %20\n\t"
      "ds_bpermute_b32 %4, %16, %21\n\t"
      "ds_bpermute_b32 %5, %16, %22\n\t"
      "ds_bpermute_b32 %6, %16, %23\n\t"
      "ds_bpermute_b32 %7, %16, %24\n\t"
      "ds_bpermute_b32 %8, %16, %25\n\t"
      "ds_bpermute_b32 %9, %16, %26\n\t"
      "ds_bpermute_b32 %10, %16, %27\n\t"
      "ds_bpermute_b32 %11, %16, %28\n\t"
      "ds_bpermute_b32 %12, %16, %29\n\t"
      "ds_bpermute_b32 %13, %16, %30\n\t"
      "ds_bpermute_b32 %14, %16, %31\n\t"
      "ds_bpermute_b32 %15, %16, %32\n\t"
      "s_waitcnt lgkmcnt(0)"
      : "=&v"(p0), "=&v"(p1), "=&v"(p2), "=&v"(p3),
        "=&v"(p4), "=&v"(p5), "=&v"(p6), "=&v"(p7),
        "=&v"(p8), "=&v"(p9), "=&v"(p10), "=&v"(p11),
        "=&v"(p12), "=&v"(p13), "=&v"(p14), "=&v"(p15)
      : "v"(addr),
        "v"(r[0]), "v"(r[1]), "v"(r[2]), "v"(r[3]),
        "v"(r[4]), "v"(r[5]), "v"(r[6]), "v"(r[7]),
        "v"(r[8]), "v"(r[9]), "v"(r[10]), "v"(r[11]),
        "v"(r[12]), "v"(r[13]), "v"(r[14]), "v"(r[15]));
  ce_keep(r[0], p0, km);   ce_keep(r[1], p1, km);
  ce_keep(r[2], p2, km);   ce_keep(r[3], p3, km);
  ce_keep(r[4], p4, km);   ce_keep(r[5], p5, km);
  ce_keep(r[6], p6, km);   ce_keep(r[7], p7, km);
  ce_keep(r[8], p8, km);   ce_keep(r[9], p9, km);
  ce_keep(r[10], p10, km); ce_keep(r[11], p11, km);
  ce_keep(r[12], p12, km); ce_keep(r[13], p13, km);
  ce_keep(r[14], p14, km); ce_keep(r[15], p15, km);
}

// shuffle stages m = MB..1 (j = 16*MB..16) + in-thread tail
template<int MB>
__device__ __forceinline__ void phase_sh(u32 (&r)[NR], int lanesh2, int tid) {
  if constexpr (MB >= 32) stage_bperm(r, lanesh2 ^ 128, (tid & 32) == 0);
  if constexpr (MB >= 16) stage_bperm(r, lanesh2 ^ 64, (tid & 16) == 0);
  if constexpr (MB >= 8) stage_bperm(r, lanesh2 ^ 32, (tid & 8) == 0);
  if constexpr (MB >= 4) stage_bperm(r, lanesh2 ^ 16, (tid & 4) == 0);
  if constexpr (MB >= 2) stage_bperm(r, lanesh2 ^ 8, (tid & 2) == 0);
  if constexpr (MB >= 1) stage_bperm(r, lanesh2 ^ 4, (tid & 1) == 0);
  tailA(r);
}

// ---------------- Kernel B: project + xy-packed flip-domain bitonic ------
__global__ __launch_bounds__(BT) void dist_kernel(const float* __restrict__ x,
                                                  const float* __restrict__ y,
                                                  const float* __restrict__ theta,
                                                  float* __restrict__ dist) {
  __shared__ u32 buf[NP];  // 16 KB slot-major exchange buffer

  const int bid = blockIdx.x;
  const int l = bid & (NL - 1);
  const int b = bid >> 7;
  const int tid = threadIdx.x;

  const float* tp = theta + ((size_t)l * NB + b) * 3;
  const float t0 = tp[0];
  const float t1 = tp[1];
  const float t2 = tp[2];

  u32 r[NR];
  {
    const float4* px = (const float4*)(x + (size_t)b * NP * ND + (size_t)tid * 48);
    const float4* py = (const float4*)(y + (size_t)b * NP * ND + (size_t)tid * 48);
#pragma unroll
    for (int g = 0; g < 4; ++g) {
      float4 XA = px[3 * g], XB = px[3 * g + 1], XC = px[3 * g + 2];
      float4 YA = py[3 * g], YB = py[3 * g + 1], YC = py[3 * g + 2];
      float x0 = XA.x * t0 + XA.y * t1 + XA.z * t2;
      float x1 = XA.w * t0 + XB.x * t1 + XB.y * t2;
      float x2 = XB.z * t0 + XB.w * t1 + XC.x * t2;
      float x3 = XC.y * t0 + XC.z * t1 + XC.w * t2;
      float y0 = YA.x * t0 + YA.y * t1 + YA.z * t2;
      float y1 = YA.w * t0 + YB.x * t1 + YB.y * t2;
      float y2 = YB.z * t0 + YB.w * t1 + YC.x * t2;
      float y3 = YC.y * t0 + YC.z * t1 + YC.w * t2;
      r[4 * g + 0] = __builtin_bit_cast(u32, __builtin_amdgcn_cvt_pkrtz(x0, y0));
      r[4 * g + 1] = __builtin_bit_cast(u32, __builtin_amdgcn_cvt_pkrtz(x1, y1));
      r[4 * g + 2] = __builtin_bit_cast(u32, __builtin_amdgcn_cvt_pkrtz(x2, y2));
      r[4 * g + 3] = __builtin_bit_cast(u32, __builtin_amdgcn_cvt_pkrtz(x3, y3));
    }
  }

  sort_k2_8(r);
  const int lanesh2 = (tid & 63) << 2;

  // k=16 (flip bit: tid&1)
  flipx(r, fmask((u32)tid & 1u));
  tailA(r);
  // k=32 .. k=1024 (flip-delta = xor of adjacent tid bits)
  flipx(r, fmask(((u32)(tid >> 0) ^ (u32)(tid >> 1)) & 1u)); phase_sh<1>(r, lanesh2, tid);
  flipx(r, fmask(((u32)(tid >> 1) ^ (u32)(tid >> 2)) & 1u)); phase_sh<2>(r, lanesh2, tid);
  flipx(r, fmask(((u32)(tid >> 2) ^ (u32)(tid >> 3)) & 1u)); phase_sh<4>(r, lanesh2, tid);
  flipx(r, fmask(((u32)(tid >> 3) ^ (u32)(tid >> 4)) & 1u)); phase_sh<8>(r, lanesh2, tid);
  flipx(r, fmask(((u32)(tid >> 4) ^ (u32)(tid >> 5)) & 1u)); phase_sh<16>(r, lanesh2, tid);
  flipx(r, fmask(((u32)(tid >> 5) ^ (u32)(tid >> 6)) & 1u)); phase_sh<32>(r, lanesh2, tid);

  // k=2048: flip, LDS stage (tid^64), shuffles m=32..1, tail
  flipx(r, fmask(((u32)(tid >> 6) ^ (u32)(tid >> 7)) & 1u));
  __syncthreads();
#pragma unroll
  for (int w = 0; w < NR; ++w) buf[w * BT + tid] = r[w];
  __syncthreads();
  {
    const bool km = (tid & 64) == 0;
#pragma unroll
    for (int w = 0; w < NR; ++w) {
      u32 p = buf[w * BT + (tid ^ 64)];
      u32 mn = pkmin(r[w], p), mx = pkmax(r[w], p);
      r[w] = km ? mn : mx;
    }
  }
  phase_sh<32>(r, lanesh2, tid);

  // k=4096: unflip (bit7), fused LDS stages j=2048 (tid^128) + j=1024 (tid^64)
  flipx(r, fmask((u32)(tid >> 7) & 1u));
  __syncthreads();
#pragma unroll
  for (int w = 0; w < NR; ++w) buf[w * BT + tid] = r[w];
  __syncthreads();
  {
    const bool a128 = (tid & 128) == 0;
    const bool a64 = (tid & 64) == 0;
#pragma unroll
    for (int w = 0; w < NR; ++w) {
      u32 av = r[w];
      u32 bv = buf[w * BT + (tid ^ 128)];
      u32 cv = buf[w * BT + (tid ^ 64)];
      u32 dv = buf[w * BT + (tid ^ 192)];
      u32 a1 = a128 ? pkmin(av, bv) : pkmax(av, bv);
      u32 c1 = a128 ? pkmin(cv, dv) : pkmax(cv, dv);  // partner lane's j=2048 result
      r[w] = a64 ? pkmin(a1, c1) : pkmax(a1, c1);
    }
  }
  phase_sh<32>(r, lanesh2, tid);

  // epilogue: sum (xs_i - ys_i)^2 = (lo - hi)^2 per reg
  float s = 0.0f;
#pragma unroll
  for (int w = 0; w < NR; ++w) {
    half2v h = __builtin_bit_cast(half2v, r[w]);
    float d = (float)h[0] - (float)h[1];
    s = fmaf(d, d, s);
  }
  for (int off = 32; off; off >>= 1) s += __shfl_down(s, off, 64);
  __syncthreads();
  float* red = (float*)buf;
  if ((tid & 63) == 0) red[tid >> 6] = s;
  __syncthreads();
  if (tid == 0) dist[l * NB + b] = red[0] + red[1] + red[2] + red[3];
}

// ---------------- Kernel C: IMH chain + loss reduction ----------------
__global__ __launch_bounds__(64) void chain_kernel(const float* __restrict__ dist,
                                                   const float* __restrict__ logu,
                                                   float* __restrict__ out) {
  const int b = threadIdx.x;
  float dold = dist[b];  // l = 0
  float sum = dold;
  for (int l = 1; l < NL; ++l) {
    float dn = dist[l * NB + b];
    float acc = fminf(0.0f, dn - dold);
    if (logu[l * NB + b] <= acc) dold = dn;
    sum += dold;
  }
  float v = sqrtf(sum * (1.0f / (float)NL));
  for (int off = 32; off; off >>= 1) v += __shfl_down(v, off, 64);
  if (b == 0) out[0] = v * (1.0f / (float)NB);
}

extern "C" void kernel_launch(void* const* d_in, const int* in_sizes, int n_in,
                              void* d_out, int out_size, void* d_ws, size_t ws_size,
                              hipStream_t stream) {
  const float* x = (const float*)d_in[0];
  const float* y = (const float*)d_in[1];
  float* out = (float*)d_out;

  float* theta = (float*)d_ws;              // NL*NB*3 floats
  float* logu = theta + NL * NB * 3;        // NL*NB floats
  float* dist = logu + NL * NB;             // NL*NB floats

  hipLaunchKernelGGL(rng_kernel, dim3(NL), dim3(128), 0, stream, theta, logu);
  hipLaunchKernelGGL(dist_kernel, dim3(NB * NL), dim3(BT), 0, stream, x, y, theta, dist);
  hipLaunchKernelGGL(chain_kernel, dim3(1), dim3(64), 0, stream, dist, logu, out);
}

// Round 9
// 254.094 us; speedup vs baseline: 4.3326x; 1.0611x over previous
//
#include <hip/hip_runtime.h>
#include <stdint.h>

#define NB 64     // batch
#define NP 4096   // points per batch
#define ND 3      // dim
#define NL 128    // chain length / projections
#define NE 64     // elements per thread; one wave (64 lanes) per (b,l) block

typedef uint32_t u32;
typedef _Float16 half2v __attribute__((ext_vector_type(2)));

// ---------------- JAX threefry2x32 (20 rounds) ----------------
__device__ __forceinline__ uint32_t rotl32(uint32_t v, int r) {
  return (v << r) | (v >> (32 - r));
}

__device__ __forceinline__ void threefry2x32(uint32_t k0, uint32_t k1,
                                             uint32_t c0, uint32_t c1,
                                             uint32_t& o0, uint32_t& o1) {
  uint32_t ks2 = k0 ^ k1 ^ 0x1BD11BDAu;
  uint32_t x0 = c0 + k0;
  uint32_t x1 = c1 + k1;
#define TF_RND(R) { x0 += x1; x1 = rotl32(x1, (R)); x1 ^= x0; }
  TF_RND(13) TF_RND(15) TF_RND(26) TF_RND(6)
  x0 += k1;  x1 += ks2 + 1u;
  TF_RND(17) TF_RND(29) TF_RND(16) TF_RND(24)
  x0 += ks2; x1 += k0 + 2u;
  TF_RND(13) TF_RND(15) TF_RND(26) TF_RND(6)
  x0 += k0;  x1 += k1 + 3u;
  TF_RND(17) TF_RND(29) TF_RND(16) TF_RND(24)
  x0 += k1;  x1 += ks2 + 4u;
  TF_RND(13) TF_RND(15) TF_RND(26) TF_RND(6)
  x0 += ks2; x1 += k0 + 5u;
#undef TF_RND
  o0 = x0; o1 = x1;
}

// ---------------- XLA ErfInv32 ----------------
__device__ __forceinline__ float erfinv_f(float x) {
  float w = -log1pf(-x * x);
  float p;
  if (w < 5.0f) {
    w = w - 2.5f;
    p = 2.81022636e-08f;
    p = fmaf(p, w, 3.43273939e-07f);
    p = fmaf(p, w, -3.5233877e-06f);
    p = fmaf(p, w, -4.39150654e-06f);
    p = fmaf(p, w, 0.00021858087f);
    p = fmaf(p, w, -0.00125372503f);
    p = fmaf(p, w, -0.00417768164f);
    p = fmaf(p, w, 0.246640727f);
    p = fmaf(p, w, 1.50140941f);
  } else {
    w = sqrtf(w) - 3.0f;
    p = -0.000200214257f;
    p = fmaf(p, w, 0.000100950558f);
    p = fmaf(p, w, 0.00134934322f);
    p = fmaf(p, w, -0.00367342844f);
    p = fmaf(p, w, 0.00573950773f);
    p = fmaf(p, w, -0.0076224613f);
    p = fmaf(p, w, 0.00943887047f);
    p = fmaf(p, w, 1.00167406f);
    p = fmaf(p, w, 2.83297682f);
  }
  return p * x;
}

__device__ __forceinline__ float bits_to_normal(uint32_t bits) {
  float f = __uint_as_float((bits >> 9) | 0x3F800000u) - 1.0f;  // [0,1)
  const float LO = -0.99999994f;  // nextafter(-1, 0)
  float u = fmaf(f, 2.0f, LO);
  u = fmaxf(LO, u);
  return 1.41421354f * erfinv_f(u);
}

__device__ __forceinline__ float bits_to_unif01(uint32_t bits) {
  float f = __uint_as_float((bits >> 9) | 0x3F800000u) - 1.0f;
  return fmaxf(0.0f, f);
}

// ---------------- Kernel A: thetas (normalized) + log-uniforms ----------
__global__ __launch_bounds__(128) void rng_kernel(float* __restrict__ theta,
                                                  float* __restrict__ logu) {
  const int l = blockIdx.x;
  const int tid = threadIdx.x;

  uint32_t kl0, kl1;
  threefry2x32(0u, 42u, 0u, (uint32_t)l, kl0, kl1);

  uint32_t na0 = kl0, na1 = kl1;
  uint32_t nb0 = 0u, nb1 = 0u;
  if (l > 0) {
    uint32_t a0, b0, a1, b1;
    threefry2x32(kl0, kl1, 0u, 2u, a0, b0);
    threefry2x32(kl0, kl1, 1u, 3u, a1, b1);
    na0 = a0; na1 = a1;
    nb0 = b0; nb1 = b1;
  }

  __shared__ float vals[NB * ND];
  if (tid < 96) {
    uint32_t o0, o1;
    threefry2x32(na0, na1, (uint32_t)tid, (uint32_t)(96 + tid), o0, o1);
    vals[tid] = bits_to_normal(o0);
    vals[96 + tid] = bits_to_normal(o1);
  }
  __syncthreads();

  if (tid < NB) {
    float v0 = vals[tid * 3 + 0];
    float v1 = vals[tid * 3 + 1];
    float v2 = vals[tid * 3 + 2];
    float s = sqrtf(v0 * v0 + v1 * v1 + v2 * v2);
    float* tp = theta + ((size_t)l * NB + tid) * 3;
    tp[0] = v0 / s;
    tp[1] = v1 / s;
    tp[2] = v2 / s;
  }

  if (l > 0 && tid < 32) {
    uint32_t o0, o1;
    threefry2x32(nb0, nb1, (uint32_t)tid, (uint32_t)(32 + tid), o0, o1);
    logu[l * NB + tid] = logf(bits_to_unif01(o0));
    logu[l * NB + 32 + tid] = logf(bits_to_unif01(o1));
  }
}

// ---------------- packed primitives ----------------
__device__ __forceinline__ u32 pkmin(u32 a, u32 b) {
  u32 d; asm("v_pk_min_f16 %0, %1, %2" : "=v"(d) : "v"(a), "v"(b)); return d;
}
__device__ __forceinline__ u32 pkmax(u32 a, u32 b) {
  u32 d; asm("v_pk_max_f16 %0, %1, %2" : "=v"(d) : "v"(a), "v"(b)); return d;
}

__device__ __forceinline__ void ceA(u32& a, u32& b) {
  u32 mn = pkmin(a, b), mx = pkmax(a, b); a = mn; b = mx;
}
__device__ __forceinline__ void ceD(u32& a, u32& b) {
  u32 mn = pkmin(a, b), mx = pkmax(a, b); a = mx; b = mn;
}

__device__ __forceinline__ u32 fmask(u32 d) {  // d in {0,1}
  return (d << 31) | (d << 15);
}

__device__ __forceinline__ void flip64(u32 (&r)[NE], u32 mask) {
#pragma unroll
  for (int w = 0; w < NE; ++w) r[w] ^= mask;
}

// in-thread ascending tail: stages j = 32,16,8,4,2,1 over the 64 regs
__device__ __forceinline__ void tail64(u32 (&r)[NE]) {
#pragma unroll
  for (int j = 32; j >= 1; j >>= 1)
#pragma unroll
    for (int v = 0; v < NE; ++v)
      if (!(v & j)) ceA(r[v], r[v | j]);
}

__device__ __forceinline__ void ce_keep(u32& a, u32 p, bool km) {
  u32 mn = pkmin(a, p), mx = pkmax(a, p);
  a = km ? mn : mx;
}

// 16 ds_bpermute in one asm block, single waitcnt (validated round 5/8)
__device__ __forceinline__ void stage_bperm16(u32 (&r)[16], int addr, bool km) {
  u32 p0, p1, p2, p3, p4, p5, p6, p7, p8, p9, p10, p11, p12, p13, p14, p15;
  asm("ds_bpermute_b32 %0, %16, %17\n\t"
      "ds_bpermute_b32 %1, %16, %18\n\t"
      "ds_bpermute_b32 %2, %16, %19\n\t"
      "ds_bpermute_b32 %3, %16, %20\n\t"
      "ds_bpermute_b32 %4, %16, %21\n\t"
      "ds_bpermute_b32 %5, %16, %22\n\t"
      "ds_bpermute_b32 %6, %16, %23\n\t"
      "ds_bpermute_b32 %7, %16, %24\n\t"
      "ds_bpermute_b32 %8, %16, %25\n\t"
      "ds_bpermute_b32 %9, %16, %26\n\t"
      "ds_bpermute_b32 %10, %16, %27\n\t"
      "ds_bpermute_b32 %11, %16, %28\n\t"
      "ds_bpermute_b32 %12, %16, %29\n\t"
      "ds_bpermute_b32 %13, %16, %30\n\t"
      "ds_bpermute_b32 %14, %16, %31\n\t"
      "ds_bpermute_b32 %15, %16, %32\n\t"
      "s_waitcnt lgkmcnt(0)"
      : "=&v"(p0), "=&v"(p1), "=&v"(p2), "=&v"(p3),
        "=&v"(p4), "=&v"(p5), "=&v"(p6), "=&v"(p7),
        "=&v"(p8), "=&v"(p9), "=&v"(p10), "=&v"(p11),
        "=&v"(p12), "=&v"(p13), "=&v"(p14), "=&v"(p15)
      : "v"(addr),
        "v"(r[0]), "v"(r[1]), "v"(r[2]), "v"(r[3]),
        "v"(r[4]), "v"(r[5]), "v"(r[6]), "v"(r[7]),
        "v"(r[8]), "v"(r[9]), "v"(r[10]), "v"(r[11]),
        "v"(r[12]), "v"(r[13]), "v"(r[14]), "v"(r[15]));
  ce_keep(r[0], p0, km);   ce_keep(r[1], p1, km);
  ce_keep(r[2], p2, km);   ce_keep(r[3], p3, km);
  ce_keep(r[4], p4, km);   ce_keep(r[5], p5, km);
  ce_keep(r[6], p6, km);   ce_keep(r[7], p7, km);
  ce_keep(r[8], p8, km);   ce_keep(r[9], p9, km);
  ce_keep(r[10], p10, km); ce_keep(r[11], p11, km);
  ce_keep(r[12], p12, km); ce_keep(r[13], p13, km);
  ce_keep(r[14], p14, km); ce_keep(r[15], p15, km);
}

__device__ __forceinline__ void stage_bperm64(u32 (&r)[NE], int addr, bool km) {
  stage_bperm16(*reinterpret_cast<u32(*)[16]>(&r[0]), addr, km);
  stage_bperm16(*reinterpret_cast<u32(*)[16]>(&r[16]), addr, km);
  stage_bperm16(*reinterpret_cast<u32(*)[16]>(&r[32]), addr, km);
  stage_bperm16(*reinterpret_cast<u32(*)[16]>(&r[48]), addr, km);
}

// cross-lane stage m=1 (quad_perm [1,0,3,2] = 0xB1) / m=2 ([2,3,0,1] = 0x4E)
// via DPP: VALU only, no DS traffic.
template<int CTRL>
__device__ __forceinline__ void stage_dpp(u32 (&r)[NE], bool km) {
#pragma unroll
  for (int v = 0; v < NE; ++v) {
    u32 p = (u32)__builtin_amdgcn_update_dpp(0, (int)r[v], CTRL, 0xF, 0xF, true);
    u32 mn = pkmin(r[v], p), mx = pkmax(r[v], p);
    r[v] = km ? mn : mx;
  }
}

// ---------------- Kernel B: 1 wave per (b,l); 64 elems/lane ----------
__global__ __launch_bounds__(64) void dist_kernel(const float* __restrict__ x,
                                                  const float* __restrict__ y,
                                                  const float* __restrict__ theta,
                                                  float* __restrict__ dist) {
  const int bid = blockIdx.x;
  const int l = bid & (NL - 1);
  const int b = bid >> 7;
  const int lane = threadIdx.x;  // 0..63

  const float* tp = theta + ((size_t)l * NB + b) * 3;
  const float t0 = tp[0];
  const float t1 = tp[1];
  const float t2 = tp[2];

  // load 64 consecutive points from each array, project, pack (x|y) per reg
  u32 r[NE];
  {
    const float4* px = (const float4*)(x + (size_t)b * NP * ND + (size_t)lane * 192);
    const float4* py = (const float4*)(y + (size_t)b * NP * ND + (size_t)lane * 192);
#pragma unroll
    for (int g = 0; g < 16; ++g) {
      float4 XA = px[3 * g], XB = px[3 * g + 1], XC = px[3 * g + 2];
      float4 YA = py[3 * g], YB = py[3 * g + 1], YC = py[3 * g + 2];
      float x0 = XA.x * t0 + XA.y * t1 + XA.z * t2;
      float x1 = XA.w * t0 + XB.x * t1 + XB.y * t2;
      float x2 = XB.z * t0 + XB.w * t1 + XC.x * t2;
      float x3 = XC.y * t0 + XC.z * t1 + XC.w * t2;
      float y0 = YA.x * t0 + YA.y * t1 + YA.z * t2;
      float y1 = YA.w * t0 + YB.x * t1 + YB.y * t2;
      float y2 = YB.z * t0 + YB.w * t1 + YC.x * t2;
      float y3 = YC.y * t0 + YC.z * t1 + YC.w * t2;
      r[4 * g + 0] = __builtin_bit_cast(u32, __builtin_amdgcn_cvt_pkrtz(x0, y0));
      r[4 * g + 1] = __builtin_bit_cast(u32, __builtin_amdgcn_cvt_pkrtz(x1, y1));
      r[4 * g + 2] = __builtin_bit_cast(u32, __builtin_amdgcn_cvt_pkrtz(x2, y2));
      r[4 * g + 3] = __builtin_bit_cast(u32, __builtin_amdgcn_cvt_pkrtz(x3, y3));
    }
  }

  // element i = lane*64 + v.  static phases k=2..32 (true domain, dir from v)
#pragma unroll
  for (int k = 2; k <= 32; k <<= 1)
#pragma unroll
    for (int j = k >> 1; j >= 1; j >>= 1)
#pragma unroll
      for (int v = 0; v < NE; ++v)
        if (!(v & j)) {
          if (!(v & k)) ceA(r[v], r[v | j]);
          else          ceD(r[v], r[v | j]);
        }

  // phase k=64: dir bit = i&64 = lane&1 -> flip, ascending tail
  flip64(r, fmask((u32)lane & 1u));
  tail64(r);

  // phases k=128..4096 (p=0..5): flip delta, cross-lane m=2^p..1, tail
  const int lanesh2 = lane << 2;
#pragma unroll 1
  for (int p = 0; p < 6; ++p) {
    flip64(r, fmask(((u32)(lane >> p) ^ (u32)(lane >> (p + 1))) & 1u));
#pragma unroll 1
    for (int m = 1 << p; m >= 4; m >>= 1)
      stage_bperm64(r, lanesh2 ^ (m << 2), (lane & m) == 0);
    if (p >= 1) stage_dpp<0x4E>(r, (lane & 2) == 0);  // m=2
    stage_dpp<0xB1>(r, (lane & 1) == 0);              // m=1
    tail64(r);
  }

  // epilogue: sum (xs_i - ys_i)^2 = (lo16 - hi16)^2 per reg, wave-reduce
  float s = 0.0f;
#pragma unroll
  for (int w = 0; w < NE; ++w) {
    half2v h = __builtin_bit_cast(half2v, r[w]);
    float d = (float)h[0] - (float)h[1];
    s = fmaf(d, d, s);
  }
#pragma unroll
  for (int off = 32; off; off >>= 1) s += __shfl_down(s, off, 64);
  if (lane == 0) dist[l * NB + b] = s;
}

// ---------------- Kernel C: IMH chain + loss reduction ----------------
__global__ __launch_bounds__(64) void chain_kernel(const float* __restrict__ dist,
                                                   const float* __restrict__ logu,
                                                   float* __restrict__ out) {
  const int b = threadIdx.x;
  float dold = dist[b];  // l = 0
  float sum = dold;
  for (int l = 1; l < NL; ++l) {
    float dn = dist[l * NB + b];
    float acc = fminf(0.0f, dn - dold);
    if (logu[l * NB + b] <= acc) dold = dn;
    sum += dold;
  }
  float v = sqrtf(sum * (1.0f / (float)NL));
  for (int off = 32; off; off >>= 1) v += __shfl_down(v, off, 64);
  if (b == 0) out[0] = v * (1.0f / (float)NB);
}

extern "C" void kernel_launch(void* const* d_in, const int* in_sizes, int n_in,
                              void* d_out, int out_size, void* d_ws, size_t ws_size,
                              hipStream_t stream) {
  const float* x = (const float*)d_in[0];
  const float* y = (const float*)d_in[1];
  float* out = (float*)d_out;

  float* theta = (float*)d_ws;              // NL*NB*3 floats
  float* logu = theta + NL * NB * 3;        // NL*NB floats
  float* dist = logu + NL * NB;             // NL*NB floats

  hipLaunchKernelGGL(rng_kernel, dim3(NL), dim3(128), 0, stream, theta, logu);
  hipLaunchKernelGGL(dist_kernel, dim3(NB * NL), dim3(64), 0, stream, x, y, theta, dist);
  hipLaunchKernelGGL(chain_kernel, dim3(1), dim3(64), 0, stream, dist, logu, out);
}

// Round 10
// 233.306 us; speedup vs baseline: 4.7186x; 1.0891x over previous
//
#include <hip/hip_runtime.h>
#include <stdint.h>

#define NB 64     // batch
#define NP 4096   // points per batch
#define ND 3      // dim
#define NL 128    // chain length / projections
#define NE 64     // elements per lane; one wave handles one (b,l) unit
#define WPB 4     // independent waves (units) per block

typedef uint32_t u32;
typedef _Float16 half2v __attribute__((ext_vector_type(2)));

// ---------------- JAX threefry2x32 (20 rounds) ----------------
__device__ __forceinline__ uint32_t rotl32(uint32_t v, int r) {
  return (v << r) | (v >> (32 - r));
}

__device__ __forceinline__ void threefry2x32(uint32_t k0, uint32_t k1,
                                             uint32_t c0, uint32_t c1,
                                             uint32_t& o0, uint32_t& o1) {
  uint32_t ks2 = k0 ^ k1 ^ 0x1BD11BDAu;
  uint32_t x0 = c0 + k0;
  uint32_t x1 = c1 + k1;
#define TF_RND(R) { x0 += x1; x1 = rotl32(x1, (R)); x1 ^= x0; }
  TF_RND(13) TF_RND(15) TF_RND(26) TF_RND(6)
  x0 += k1;  x1 += ks2 + 1u;
  TF_RND(17) TF_RND(29) TF_RND(16) TF_RND(24)
  x0 += ks2; x1 += k0 + 2u;
  TF_RND(13) TF_RND(15) TF_RND(26) TF_RND(6)
  x0 += k0;  x1 += k1 + 3u;
  TF_RND(17) TF_RND(29) TF_RND(16) TF_RND(24)
  x0 += k1;  x1 += ks2 + 4u;
  TF_RND(13) TF_RND(15) TF_RND(26) TF_RND(6)
  x0 += ks2; x1 += k0 + 5u;
#undef TF_RND
  o0 = x0; o1 = x1;
}

// ---------------- XLA ErfInv32 ----------------
__device__ __forceinline__ float erfinv_f(float x) {
  float w = -log1pf(-x * x);
  float p;
  if (w < 5.0f) {
    w = w - 2.5f;
    p = 2.81022636e-08f;
    p = fmaf(p, w, 3.43273939e-07f);
    p = fmaf(p, w, -3.5233877e-06f);
    p = fmaf(p, w, -4.39150654e-06f);
    p = fmaf(p, w, 0.00021858087f);
    p = fmaf(p, w, -0.00125372503f);
    p = fmaf(p, w, -0.00417768164f);
    p = fmaf(p, w, 0.246640727f);
    p = fmaf(p, w, 1.50140941f);
  } else {
    w = sqrtf(w) - 3.0f;
    p = -0.000200214257f;
    p = fmaf(p, w, 0.000100950558f);
    p = fmaf(p, w, 0.00134934322f);
    p = fmaf(p, w, -0.00367342844f);
    p = fmaf(p, w, 0.00573950773f);
    p = fmaf(p, w, -0.0076224613f);
    p = fmaf(p, w, 0.00943887047f);
    p = fmaf(p, w, 1.00167406f);
    p = fmaf(p, w, 2.83297682f);
  }
  return p * x;
}

__device__ __forceinline__ float bits_to_normal(uint32_t bits) {
  float f = __uint_as_float((bits >> 9) | 0x3F800000u) - 1.0f;  // [0,1)
  const float LO = -0.99999994f;  // nextafter(-1, 0)
  float u = fmaf(f, 2.0f, LO);
  u = fmaxf(LO, u);
  return 1.41421354f * erfinv_f(u);
}

__device__ __forceinline__ float bits_to_unif01(uint32_t bits) {
  float f = __uint_as_float((bits >> 9) | 0x3F800000u) - 1.0f;
  return fmaxf(0.0f, f);
}

// ---------------- Kernel A: thetas (normalized) + log-uniforms ----------
__global__ __launch_bounds__(128) void rng_kernel(float* __restrict__ theta,
                                                  float* __restrict__ logu) {
  const int l = blockIdx.x;
  const int tid = threadIdx.x;

  uint32_t kl0, kl1;
  threefry2x32(0u, 42u, 0u, (uint32_t)l, kl0, kl1);

  uint32_t na0 = kl0, na1 = kl1;
  uint32_t nb0 = 0u, nb1 = 0u;
  if (l > 0) {
    uint32_t a0, b0, a1, b1;
    threefry2x32(kl0, kl1, 0u, 2u, a0, b0);
    threefry2x32(kl0, kl1, 1u, 3u, a1, b1);
    na0 = a0; na1 = a1;
    nb0 = b0; nb1 = b1;
  }

  __shared__ float vals[NB * ND];
  if (tid < 96) {
    uint32_t o0, o1;
    threefry2x32(na0, na1, (uint32_t)tid, (uint32_t)(96 + tid), o0, o1);
    vals[tid] = bits_to_normal(o0);
    vals[96 + tid] = bits_to_normal(o1);
  }
  __syncthreads();

  if (tid < NB) {
    float v0 = vals[tid * 3 + 0];
    float v1 = vals[tid * 3 + 1];
    float v2 = vals[tid * 3 + 2];
    float s = sqrtf(v0 * v0 + v1 * v1 + v2 * v2);
    float* tp = theta + ((size_t)l * NB + tid) * 3;
    tp[0] = v0 / s;
    tp[1] = v1 / s;
    tp[2] = v2 / s;
  }

  if (l > 0 && tid < 32) {
    uint32_t o0, o1;
    threefry2x32(nb0, nb1, (uint32_t)tid, (uint32_t)(32 + tid), o0, o1);
    logu[l * NB + tid] = logf(bits_to_unif01(o0));
    logu[l * NB + 32 + tid] = logf(bits_to_unif01(o1));
  }
}

// ---------------- packed primitives ----------------
__device__ __forceinline__ u32 pkmin(u32 a, u32 b) {
  u32 d; asm("v_pk_min_f16 %0, %1, %2" : "=v"(d) : "v"(a), "v"(b)); return d;
}
__device__ __forceinline__ u32 pkmax(u32 a, u32 b) {
  u32 d; asm("v_pk_max_f16 %0, %1, %2" : "=v"(d) : "v"(a), "v"(b)); return d;
}

__device__ __forceinline__ void ceA(u32& a, u32& b) {
  u32 mn = pkmin(a, b), mx = pkmax(a, b); a = mn; b = mx;
}
__device__ __forceinline__ void ceD(u32& a, u32& b) {
  u32 mn = pkmin(a, b), mx = pkmax(a, b); a = mx; b = mn;
}

__device__ __forceinline__ u32 fmask(u32 d) {  // d in {0,1}
  return (d << 31) | (d << 15);
}

__device__ __forceinline__ void flip64(u32 (&r)[NE], u32 mask) {
#pragma unroll
  for (int w = 0; w < NE; ++w) r[w] ^= mask;
}

// in-thread ascending tail: stages j = 32,16,8,4,2,1 over the 64 regs
__device__ __forceinline__ void tail64(u32 (&r)[NE]) {
#pragma unroll
  for (int j = 32; j >= 1; j >>= 1)
#pragma unroll
    for (int v = 0; v < NE; ++v)
      if (!(v & j)) ceA(r[v], r[v | j]);
}

__device__ __forceinline__ void ce_keep(u32& a, u32 p, bool km) {
  u32 mn = pkmin(a, p), mx = pkmax(a, p);
  a = km ? mn : mx;
}

// 16 ds_bpermute in one asm block, single waitcnt (validated rounds 5/8/9)
__device__ __forceinline__ void stage_bperm16(u32 (&r)[16], int addr, bool km) {
  u32 p0, p1, p2, p3, p4, p5, p6, p7, p8, p9, p10, p11, p12, p13, p14, p15;
  asm("ds_bpermute_b32 %0, %16, %17\n\t"
      "ds_bpermute_b32 %1, %16, %18\n\t"
      "ds_bpermute_b32 %2, %16, %19\n\t"
      "ds_bpermute_b32 %3, %16, %20\n\t"
      "ds_bpermute_b32 %4, %16, %21\n\t"
      "ds_bpermute_b32 %5, %16, %22\n\t"
      "ds_bpermute_b32 %6, %16, %23\n\t"
      "ds_bpermute_b32 %7, %16, %24\n\t"
      "ds_bpermute_b32 %8, %16, %25\n\t"
      "ds_bpermute_b32 %9, %16, %26\n\t"
      "ds_bpermute_b32 %10, %16, %27\n\t"
      "ds_bpermute_b32 %11, %16, %28\n\t"
      "ds_bpermute_b32 %12, %16, %29\n\t"
      "ds_bpermute_b32 %13, %16, %30\n\t"
      "ds_bpermute_b32 %14, %16, %31\n\t"
      "ds_bpermute_b32 %15, %16, %32\n\t"
      "s_waitcnt lgkmcnt(0)"
      : "=&v"(p0), "=&v"(p1), "=&v"(p2), "=&v"(p3),
        "=&v"(p4), "=&v"(p5), "=&v"(p6), "=&v"(p7),
        "=&v"(p8), "=&v"(p9), "=&v"(p10), "=&v"(p11),
        "=&v"(p12), "=&v"(p13), "=&v"(p14), "=&v"(p15)
      : "v"(addr),
        "v"(r[0]), "v"(r[1]), "v"(r[2]), "v"(r[3]),
        "v"(r[4]), "v"(r[5]), "v"(r[6]), "v"(r[7]),
        "v"(r[8]), "v"(r[9]), "v"(r[10]), "v"(r[11]),
        "v"(r[12]), "v"(r[13]), "v"(r[14]), "v"(r[15]));
  ce_keep(r[0], p0, km);   ce_keep(r[1], p1, km);
  ce_keep(r[2], p2, km);   ce_keep(r[3], p3, km);
  ce_keep(r[4], p4, km);   ce_keep(r[5], p5, km);
  ce_keep(r[6], p6, km);   ce_keep(r[7], p7, km);
  ce_keep(r[8], p8, km);   ce_keep(r[9], p9, km);
  ce_keep(r[10], p10, km); ce_keep(r[11], p11, km);
  ce_keep(r[12], p12, km); ce_keep(r[13], p13, km);
  ce_keep(r[14], p14, km); ce_keep(r[15], p15, km);
}

__device__ __forceinline__ void stage_bperm64(u32 (&r)[NE], int addr, bool km) {
  stage_bperm16(*reinterpret_cast<u32(*)[16]>(&r[0]), addr, km);
  stage_bperm16(*reinterpret_cast<u32(*)[16]>(&r[16]), addr, km);
  stage_bperm16(*reinterpret_cast<u32(*)[16]>(&r[32]), addr, km);
  stage_bperm16(*reinterpret_cast<u32(*)[16]>(&r[48]), addr, km);
}

// cross-lane stage m=1 (quad_perm [1,0,3,2] = 0xB1) / m=2 ([2,3,0,1] = 0x4E)
// via DPP: VALU only, no DS traffic.
template<int CTRL>
__device__ __forceinline__ void stage_dpp(u32 (&r)[NE], bool km) {
#pragma unroll
  for (int v = 0; v < NE; ++v) {
    u32 p = (u32)__builtin_amdgcn_update_dpp(0, (int)r[v], CTRL, 0xF, 0xF, true);
    u32 mn = pkmin(r[v], p), mx = pkmax(r[v], p);
    r[v] = km ? mn : mx;
  }
}

// ---------------- Kernel B: 4 independent waves/block; 64 elems/lane -----
__global__ __launch_bounds__(WPB * 64) void dist_kernel(const float* __restrict__ x,
                                                        const float* __restrict__ y,
                                                        const float* __restrict__ theta,
                                                        float* __restrict__ dist) {
  const int unit = blockIdx.x * WPB + (threadIdx.x >> 6);  // (b,l) unit
  const int l = unit & (NL - 1);
  const int b = unit >> 7;
  const int lane = threadIdx.x & 63;

  const float* tp = theta + ((size_t)l * NB + b) * 3;
  const float t0 = tp[0];
  const float t1 = tp[1];
  const float t2 = tp[2];

  // load 64 consecutive points from each array, project, pack (x|y) per reg
  u32 r[NE];
  {
    const float4* px = (const float4*)(x + (size_t)b * NP * ND + (size_t)lane * 192);
    const float4* py = (const float4*)(y + (size_t)b * NP * ND + (size_t)lane * 192);
#pragma unroll
    for (int g = 0; g < 16; ++g) {
      float4 XA = px[3 * g], XB = px[3 * g + 1], XC = px[3 * g + 2];
      float4 YA = py[3 * g], YB = py[3 * g + 1], YC = py[3 * g + 2];
      float x0 = XA.x * t0 + XA.y * t1 + XA.z * t2;
      float x1 = XA.w * t0 + XB.x * t1 + XB.y * t2;
      float x2 = XB.z * t0 + XB.w * t1 + XC.x * t2;
      float x3 = XC.y * t0 + XC.z * t1 + XC.w * t2;
      float y0 = YA.x * t0 + YA.y * t1 + YA.z * t2;
      float y1 = YA.w * t0 + YB.x * t1 + YB.y * t2;
      float y2 = YB.z * t0 + YB.w * t1 + YC.x * t2;
      float y3 = YC.y * t0 + YC.z * t1 + YC.w * t2;
      r[4 * g + 0] = __builtin_bit_cast(u32, __builtin_amdgcn_cvt_pkrtz(x0, y0));
      r[4 * g + 1] = __builtin_bit_cast(u32, __builtin_amdgcn_cvt_pkrtz(x1, y1));
      r[4 * g + 2] = __builtin_bit_cast(u32, __builtin_amdgcn_cvt_pkrtz(x2, y2));
      r[4 * g + 3] = __builtin_bit_cast(u32, __builtin_amdgcn_cvt_pkrtz(x3, y3));
    }
  }

  // element i = lane*64 + v.  static phases k=2..32 (true domain, dir from v)
#pragma unroll
  for (int k = 2; k <= 32; k <<= 1)
#pragma unroll
    for (int j = k >> 1; j >= 1; j >>= 1)
#pragma unroll
      for (int v = 0; v < NE; ++v)
        if (!(v & j)) {
          if (!(v & k)) ceA(r[v], r[v | j]);
          else          ceD(r[v], r[v | j]);
        }

  // phase k=64: dir bit = i&64 = lane&1 -> flip, ascending tail
  flip64(r, fmask((u32)lane & 1u));
  tail64(r);

  // phases k=128..4096 (p=0..5): flip delta, cross-lane m=2^p..1, tail
  const int lanesh2 = lane << 2;
#pragma unroll 1
  for (int p = 0; p < 6; ++p) {
    flip64(r, fmask(((u32)(lane >> p) ^ (u32)(lane >> (p + 1))) & 1u));
#pragma unroll 1
    for (int m = 1 << p; m >= 4; m >>= 1)
      stage_bperm64(r, lanesh2 ^ (m << 2), (lane & m) == 0);
    if (p >= 1) stage_dpp<0x4E>(r, (lane & 2) == 0);  // m=2
    stage_dpp<0xB1>(r, (lane & 1) == 0);              // m=1
    tail64(r);
  }

  // epilogue: sum (xs_i - ys_i)^2 = (lo16 - hi16)^2 per reg, wave-reduce
  float s = 0.0f;
#pragma unroll
  for (int w = 0; w < NE; ++w) {
    half2v h = __builtin_bit_cast(half2v, r[w]);
    float d = (float)h[0] - (float)h[1];
    s = fmaf(d, d, s);
  }
#pragma unroll
  for (int off = 32; off; off >>= 1) s += __shfl_down(s, off, 64);
  if (lane == 0) dist[l * NB + b] = s;
}

// ---------------- Kernel C: IMH chain + loss reduction ----------------
__global__ __launch_bounds__(64) void chain_kernel(const float* __restrict__ dist,
                                                   const float* __restrict__ logu,
                                                   float* __restrict__ out) {
  const int b = threadIdx.x;
  float dold = dist[b];  // l = 0
  float sum = dold;
  for (int l = 1; l < NL; ++l) {
    float dn = dist[l * NB + b];
    float acc = fminf(0.0f, dn - dold);
    if (logu[l * NB + b] <= acc) dold = dn;
    sum += dold;
  }
  float v = sqrtf(sum * (1.0f / (float)NL));
  for (int off = 32; off; off >>= 1) v += __shfl_down(v, off, 64);
  if (b == 0) out[0] = v * (1.0f / (float)NB);
}

extern "C" void kernel_launch(void* const* d_in, const int* in_sizes, int n_in,
                              void* d_out, int out_size, void* d_ws, size_t ws_size,
                              hipStream_t stream) {
  const float* x = (const float*)d_in[0];
  const float* y = (const float*)d_in[1];
  float* out = (float*)d_out;

  float* theta = (float*)d_ws;              // NL*NB*3 floats
  float* logu = theta + NL * NB * 3;        // NL*NB floats
  float* dist = logu + NL * NB;             // NL*NB floats

  hipLaunchKernelGGL(rng_kernel, dim3(NL), dim3(128), 0, stream, theta, logu);
  hipLaunchKernelGGL(dist_kernel, dim3(NB * NL / WPB), dim3(WPB * 64), 0, stream,
                     x, y, theta, dist);
  hipLaunchKernelGGL(chain_kernel, dim3(1), dim3(64), 0, stream, dist, logu, out);
}